// Round 5
// baseline (421.762 us; speedup 1.0000x reference)
//
#include <hip/hip_runtime.h>

#define Bb 2
#define Tt 2048
#define Dd 1024
#define Hh 16
#define LDC 4480

typedef __attribute__((ext_vector_type(8))) short s16x8;
typedef __attribute__((ext_vector_type(4))) float f32x4;
typedef __attribute__((ext_vector_type(4))) _Float16 f16x4;

__device__ __forceinline__ float bf2f(unsigned short u) {
  unsigned v = ((unsigned)u) << 16;
  union { unsigned u; float f; } c; c.u = v; return c.f;
}
__device__ __forceinline__ unsigned short f2bf(float f) {
  union { float f; unsigned u; } c; c.f = f;
  unsigned u = c.u + 0x7fffu + ((c.u >> 16) & 1u);
  return (unsigned short)(u >> 16);
}
__device__ __forceinline__ float sigm(float x) { return 1.f / (1.f + expf(-x)); }

__device__ __forceinline__ void async_copy16(void* lds, const void* g) {
  __builtin_amdgcn_global_load_lds(
      (const __attribute__((address_space(1))) unsigned int*)g,
      (__attribute__((address_space(3))) unsigned int*)lds, 16, 0, 0);
}

// ---------------- cast x to bf16 ----------------

__global__ __launch_bounds__(256) void cast_x_kernel(const float* __restrict__ x,
                                                     unsigned short* __restrict__ xb) {
  int i = blockIdx.x * 256 + threadIdx.x;
  const float4* xv = reinterpret_cast<const float4*>(x);
  float4 v = xv[i];
  unsigned long long pk = (unsigned long long)f2bf(v.x)
                        | ((unsigned long long)f2bf(v.y) << 16)
                        | ((unsigned long long)f2bf(v.z) << 32)
                        | ((unsigned long long)f2bf(v.w) << 48);
  reinterpret_cast<unsigned long long*>(xb)[i] = pk;
}

// ---------------- fused weight concat + transpose + cast ----------------

__global__ __launch_bounds__(256) void build_wt_kernel(const float* __restrict__ qkv_w,
                                                       const float* __restrict__ w1w,
                                                       const float* __restrict__ w2w,
                                                       const float* __restrict__ w1r,
                                                       const float* __restrict__ w2r,
                                                       const float* __restrict__ memg_w,
                                                       const float* __restrict__ memv_w,
                                                       unsigned short* __restrict__ WT) {
  __shared__ float tile[32][33];
  int n0 = blockIdx.x * 32, k0 = blockIdx.y * 32;
  int tx = threadIdx.x & 31, ty = threadIdx.x >> 5;
#pragma unroll
  for (int i = 0; i < 4; i++) {
    int k = k0 + ty + i * 8, n = n0 + tx;
    float v;
    if (n < 3072)       v = qkv_w[(size_t)k * 3072 + n];
    else if (n < 3136)  v = w1w[k * 64 + (n - 3072)];
    else if (n < 3200)  v = w2w[k * 64 + (n - 3136)];
    else if (n < 3264)  v = w1r[k * 64 + (n - 3200)];
    else if (n < 3328)  v = w2r[k * 64 + (n - 3264)];
    else if (n < 3344)  v = memg_w[k * 16 + (n - 3328)];
    else if (n < 3392)  v = 0.f;
    else if (n < 4416)  v = memv_w[(size_t)k * 1024 + (n - 3392)];
    else                v = 0.f;
    tile[ty + i * 8][tx] = v;
  }
  __syncthreads();
#pragma unroll
  for (int i = 0; i < 4; i++) {
    int n = n0 + ty + i * 8, k = k0 + tx;
    WT[(size_t)n * 1024 + k] = f2bf(tile[tx][ty + i * 8]);
  }
}

// src: (1024, ncols) fp32 row-major -> dst: (ncols, 1024) bf16 row-major
__global__ __launch_bounds__(256) void transpose_cast_kernel(const float* __restrict__ src,
                                                             int ncols,
                                                             unsigned short* __restrict__ dst) {
  __shared__ float tile[32][33];
  int n0 = blockIdx.x * 32, k0 = blockIdx.y * 32;
  int tx = threadIdx.x & 31, ty = threadIdx.x >> 5;
#pragma unroll
  for (int i = 0; i < 4; i++) {
    int k = k0 + ty + i * 8, n = n0 + tx;
    tile[ty + i * 8][tx] = (n < ncols) ? src[(size_t)k * ncols + n] : 0.f;
  }
  __syncthreads();
#pragma unroll
  for (int i = 0; i < 4; i++) {
    int n = n0 + ty + i * 8, k = k0 + tx;
    if (n < ncols) dst[(size_t)n * 1024 + k] = f2bf(tile[tx][ty + i * 8]);
  }
}

__global__ void bias_fill_kernel(const float* __restrict__ qkv_b,
                                 const float* __restrict__ memg_b,
                                 const float* __restrict__ memv_b,
                                 float* __restrict__ bias) {
  int i = blockIdx.x * 256 + threadIdx.x;
  if (i >= LDC) return;
  float v = 0.f;
  if (i < 3072) v = qkv_b[i];
  else if (i >= 3328 && i < 3344) v = memg_b[i - 3328];
  else if (i >= 3392 && i < 4416) v = memv_b[i - 3392];
  bias[i] = v;
}

// ---------------- bf16 MFMA GEMM: C(M,N) = A(M,K) * B^T(N,K) + bias ----------------

template <bool OUT_BF16>
__global__ __launch_bounds__(256) void gemm_kernel(const unsigned short* __restrict__ A,
                                                   const unsigned short* __restrict__ Bt,
                                                   void* __restrict__ Cout,
                                                   const float* __restrict__ bias,
                                                   int M, int N, int K) {
  __shared__ unsigned short As[128 * 32];
  __shared__ unsigned short Bs[128 * 32];
  const int tid = threadIdx.x;
  const int lane = tid & 63, wid = tid >> 6;
  const int quad = lane >> 4, c16 = lane & 15;
  const int mBase = blockIdx.y * 128, nBase = blockIdx.x * 128;
  const int wm = wid >> 1, wn = wid & 1;
  const int srow = lane >> 2, scol = (lane & 3) << 3;

  f32x4 acc[4][4] = {};
  for (int k0 = 0; k0 < K; k0 += 32) {
    __syncthreads();
#pragma unroll
    for (int j = 0; j < 2; j++) {
      int rr = wid * 32 + j * 16;
      async_copy16(&As[rr * 32], &A[(size_t)(mBase + rr + srow) * K + k0 + scol]);
      async_copy16(&Bs[rr * 32], &Bt[(size_t)(nBase + rr + srow) * K + k0 + scol]);
    }
    __syncthreads();
    s16x8 af[4], bf[4];
#pragma unroll
    for (int mt = 0; mt < 4; mt++)
      af[mt] = *(const s16x8*)&As[(wm * 64 + mt * 16 + c16) * 32 + quad * 8];
#pragma unroll
    for (int nt = 0; nt < 4; nt++)
      bf[nt] = *(const s16x8*)&Bs[(wn * 64 + nt * 16 + c16) * 32 + quad * 8];
#pragma unroll
    for (int mt = 0; mt < 4; mt++)
#pragma unroll
      for (int nt = 0; nt < 4; nt++)
        acc[mt][nt] = __builtin_amdgcn_mfma_f32_16x16x32_bf16(af[mt], bf[nt], acc[mt][nt], 0, 0, 0);
  }
#pragma unroll
  for (int mt = 0; mt < 4; mt++)
#pragma unroll
    for (int nt = 0; nt < 4; nt++) {
      int col = nBase + wn * 64 + nt * 16 + c16;
      float bv = bias[col];
#pragma unroll
      for (int r = 0; r < 4; r++) {
        int row = mBase + wm * 64 + mt * 16 + quad * 4 + r;
        float v = acc[mt][nt][r] + bv;
        if (OUT_BF16)
          ((unsigned short*)Cout)[(size_t)row * N + col] = f2bf(v);
        else
          ((float*)Cout)[(size_t)row * N + col] = v;
      }
    }
}

// ---------------- repack K compact (bf16) + V transposed (f16!) ----------------

__global__ __launch_bounds__(256) void repack_kernel(const unsigned short* __restrict__ Cq,
                                                     unsigned short* __restrict__ Kc,
                                                     unsigned short* __restrict__ Vt) {
  int tb = blockIdx.x & 31, h = (blockIdx.x >> 5) & 15, b = blockIdx.x >> 9;
  int tid = threadIdx.x;
  __shared__ unsigned short vtile[64][68];
  int row = tid >> 2, col0 = (tid & 3) * 16;
  int t = tb * 64 + row;
  size_t src = (size_t)(b * Tt + t) * LDC + h * 64 + col0;
  s16x8 k0 = *(const s16x8*)&Cq[src + 1024];
  s16x8 k1 = *(const s16x8*)&Cq[src + 1024 + 8];
  size_t kdst = ((size_t)(b * Hh + h) * Tt + t) * 64 + col0;
  *(s16x8*)&Kc[kdst] = k0;
  *(s16x8*)&Kc[kdst + 8] = k1;
  s16x8 v0 = *(const s16x8*)&Cq[src + 2048];
  s16x8 v1 = *(const s16x8*)&Cq[src + 2048 + 8];
#pragma unroll
  for (int e = 0; e < 8; e++) {
    // bf16 -> f16 conversion for the PV f16 MFMA path
    union { _Float16 h; unsigned short s; } c0h, c1h;
    c0h.h = (_Float16)bf2f((unsigned short)v0[e]);
    c1h.h = (_Float16)bf2f((unsigned short)v1[e]);
    vtile[row][col0 + e] = c0h.s;
    vtile[row][col0 + 8 + e] = c1h.s;
  }
  __syncthreads();
  int tloc = tid & 63, dbase = (tid >> 6) * 16;
  size_t vb = ((size_t)(b * Hh + h) * 64) * Tt + tb * 64 + tloc;
#pragma unroll
  for (int dd = 0; dd < 16; dd++) {
    int d = dbase + dd;
    Vt[vb + (size_t)d * Tt] = vtile[tloc][d];
  }
}

// ---------------- MFMA flash attention: S^T trick, no LDS, paired + key-split ----
// S^T = K*Q^T (operand swap): C-layout lane holds P[qrow=lane&15][key=quad*4+r],
// which IS the A-operand fragment of mfma_f32_16x16x16f16 -> PV directly from
// registers. Fixed-max softmax (scores tiny) -> partials additive across chunks.
// Wave = (pair pi, chunk c). c0: tile A fully + tile B keys [0,1024).
// c1: tile B keys [1024, nkB). 4096 waves, zero LDS.

__device__ __forceinline__ void tile16(int key0, int q0, bool mask, int quad, int c16,
                                       const s16x8& kf0, const s16x8& kf1,
                                       const s16x8& qf0, const s16x8& qf1,
                                       const f16x4 vfh[4],
                                       float& l_i, f32x4 o[4]) {
  f32x4 st = {};
  st = __builtin_amdgcn_mfma_f32_16x16x32_bf16(kf0, qf0, st, 0, 0, 0);
  st = __builtin_amdgcn_mfma_f32_16x16x32_bf16(kf1, qf1, st, 0, 0, 0);
  f16x4 pa;
  float lp = 0.f;
#pragma unroll
  for (int r = 0; r < 4; r++) {
    float v = st[r] * 0.125f;
    if (mask) v = (key0 + quad * 4 + r <= q0 + c16) ? v : -1e30f;
    float p = __expf(v);
    lp += p;
    pa[r] = (_Float16)p;
  }
  l_i += lp;
#pragma unroll
  for (int nt = 0; nt < 4; nt++)
    o[nt] = __builtin_amdgcn_mfma_f32_16x16x16f16(pa, vfh[nt], o[nt], 0, 0, 0);
}

__global__ __launch_bounds__(256) void attn_kernel(const unsigned short* __restrict__ Cq,
                                                   const unsigned short* __restrict__ Kc,
                                                   const unsigned short* __restrict__ Vt,
                                                   unsigned short* __restrict__ po,
                                                   float* __restrict__ pll) {
  const int w = threadIdx.x >> 6, lane = threadIdx.x & 63;
  const int f = blockIdx.x * 4 + w;           // 0..127
  const int pi = f >> 1, c = f & 1;
  const int bh = blockIdx.y, b = bh >> 4, h = bh & 15;
  const int quad = lane >> 4, c16 = lane & 15;
  const int qA = pi * 16, qB = (127 - pi) * 16;
  const int nkA = qA + 16, nkB = qB + 16;

  size_t rowB = (size_t)(b * Tt + qB + c16) * LDC + h * 64;
  s16x8 qB0 = *(const s16x8*)&Cq[rowB + quad * 8];
  s16x8 qB1 = *(const s16x8*)&Cq[rowB + 32 + quad * 8];
  s16x8 qA0, qA1;
  if (c == 0) {
    size_t rowA = (size_t)(b * Tt + qA + c16) * LDC + h * 64;
    qA0 = *(const s16x8*)&Cq[rowA + quad * 8];
    qA1 = *(const s16x8*)&Cq[rowA + 32 + quad * 8];
  }

  const unsigned short* Kb = Kc + (size_t)bh * Tt * 64;
  const unsigned short* Vb = Vt + (size_t)bh * 64 * Tt;

  float lA = 0.f, lB = 0.f;
  f32x4 oA[4] = {}, oB[4] = {};

  const int kstart = c << 10;
  const int kendB = (c == 0) ? 1024 : nkB;

  for (int ks = kstart; ks < kendB; ks += 32) {
    s16x8 kf[2][2];
    f16x4 vfh[2][4];
#pragma unroll
    for (int g = 0; g < 2; g++) {
      const unsigned short* kr = Kb + (size_t)(ks + g * 16 + c16) * 64 + quad * 8;
      kf[g][0] = *(const s16x8*)kr;
      kf[g][1] = *(const s16x8*)(kr + 32);
#pragma unroll
      for (int nt = 0; nt < 4; nt++)
        vfh[g][nt] = *(const f16x4*)(Vb + (size_t)(nt * 16 + c16) * Tt + ks + g * 16 + quad * 4);
    }
    bool maskB = (ks + 31 > qB);  // false for all c0 steps (qB >= 1024)
#pragma unroll
    for (int g = 0; g < 2; g++)
      tile16(ks + g * 16, qB, maskB, quad, c16, kf[g][0], kf[g][1], qB0, qB1, vfh[g], lB, oB);
    if (c == 0 && ks < nkA) {
      bool maskA = (ks + 31 > qA);
#pragma unroll
      for (int g = 0; g < 2; g++)
        tile16(ks + g * 16, qA, maskA, quad, c16, kf[g][0], kf[g][1], qA0, qA1, vfh[g], lA, oA);
    }
  }

  // l: per-lane partial holds qrow = c16; reduce across the 4 quads
  lB += __shfl_xor(lB, 16, 64);
  lB += __shfl_xor(lB, 32, 64);
  if (lane < 16) pll[(size_t)(c * 32 + bh) * Tt + qB + lane] = lB;
#pragma unroll
  for (int r = 0; r < 4; r++) {
    int row = qB + quad * 4 + r;
    size_t base = ((size_t)(c * 2 + b) * Tt + row) * Dd + h * 64;
#pragma unroll
    for (int nt = 0; nt < 4; nt++)
      po[base + nt * 16 + c16] = f2bf(oB[nt][r]);
  }
  if (c == 0) {
    lA += __shfl_xor(lA, 16, 64);
    lA += __shfl_xor(lA, 32, 64);
    if (lane < 16) pll[(size_t)bh * Tt + qA + lane] = lA;
#pragma unroll
    for (int r = 0; r < 4; r++) {
      int row = qA + quad * 4 + r;
      size_t base = ((size_t)b * Tt + row) * Dd + h * 64;
#pragma unroll
      for (int nt = 0; nt < 4; nt++)
        po[base + nt * 16 + c16] = f2bf(oA[nt][r]);
    }
  }
}

// ---------------- Plucker lines ----------------

__device__ __forceinline__ void ext6(const float* p, const float* q, float* L) {
  L[0] = p[0] * q[1] - p[1] * q[0];
  L[1] = p[0] * q[2] - p[2] * q[0];
  L[2] = p[0] * q[3] - p[3] * q[0];
  L[3] = p[1] * q[2] - p[2] * q[1];
  L[4] = p[1] * q[3] - p[3] * q[1];
  L[5] = p[2] * q[3] - p[3] * q[2];
  float n = sqrtf(L[0]*L[0] + L[1]*L[1] + L[2]*L[2] + L[3]*L[3] + L[4]*L[4] + L[5]*L[5]);
  float inv = 1.f / fmaxf(n, 1e-12f);
#pragma unroll
  for (int k = 0; k < 6; k++) L[k] *= inv;
}

__global__ void lines_kernel(const unsigned short* __restrict__ Cq,
                             float* __restrict__ Jw, float* __restrict__ Jr,
                             float* __restrict__ rd) {
  int idx = blockIdx.x * 256 + threadIdx.x;
  int h = idx & 15, t = (idx >> 4) & 2047, b = idx >> 15;
  size_t row = (size_t)(b * Tt + t) * LDC;
  float w1[4], w2[4], r1[4], r2[4];
#pragma unroll
  for (int k = 0; k < 4; k++) {
    w1[k] = (t > 0) ? bf2f(Cq[row - LDC + 3072 + h * 4 + k]) : 0.f;
    w2[k] = bf2f(Cq[row + 3136 + h * 4 + k]);
    r1[k] = bf2f(Cq[row + 3200 + h * 4 + k]);
    r2[k] = bf2f(Cq[row + 3264 + h * 4 + k]);
  }
  float Lw[6], Lr[6];
  ext6(w1, w2, Lw);
  ext6(r1, r2, Lr);
  size_t ob = ((size_t)(b * Hh + h) * Tt + t) * 6;
  Jw[ob + 0] = Lw[5]; Jw[ob + 1] = -Lw[4]; Jw[ob + 2] = Lw[3];
  Jw[ob + 3] = Lw[2]; Jw[ob + 4] = -Lw[1]; Jw[ob + 5] = Lw[0];
  Jr[ob + 0] = Lr[5]; Jr[ob + 1] = -Lr[4]; Jr[ob + 2] = Lr[3];
  Jr[ob + 3] = Lr[2]; Jr[ob + 4] = -Lr[1]; Jr[ob + 5] = Lr[0];
#pragma unroll
  for (int k = 0; k < 6; k++) rd[ob + k] = Lr[k];
}

// ---------------- chunked decay scan ----------------

__global__ __launch_bounds__(64) void scanA_kernel(const float* __restrict__ Jw,
                                                   const float* __restrict__ Jr,
                                                   const float* __restrict__ decay_logits,
                                                   float* __restrict__ chunkA) {
  int blk = blockIdx.x;
  int chunk = blk & 15, bh = (blk >> 4) & 31, type = blk >> 9;
  int lane = threadIdx.x;
  const float* V = (type == 0 ? Jw : Jr) + ((size_t)bh * Tt + chunk * 128) * 6;
  __shared__ float v[768];
  for (int i = lane; i < 768; i += 64) v[i] = V[i];
  __syncthreads();
  float d = sigm(decay_logits[bh & 15]);
  int ll = lane < 36 ? lane : 35;
  int i6 = ll / 6, j6 = ll % 6;
  float A = 0.f;
  for (int s = 0; s < 128; s++) A = d * A + v[s * 6 + i6] * v[s * 6 + j6];
  if (lane < 36) chunkA[((size_t)(type * 32 + bh) * 16 + chunk) * 36 + lane] = A;
}

__global__ void scanA2_kernel(const float* __restrict__ chunkA,
                              const float* __restrict__ decay_logits,
                              float* __restrict__ Bst) {
  int idx = blockIdx.x * 256 + threadIdx.x;
  if (idx >= 2 * 32 * 36) return;
  int entry = idx % 36, bh = (idx / 36) % 32, type = idx / (36 * 32);
  float d = sigm(decay_logits[bh & 15]);
  float dS = powf(d, 128.f);
  float Bv = 0.f;
  size_t base = (size_t)(type * 32 + bh) * 16;
  for (int c = 0; c < 16; c++) {
    Bst[(base + c) * 36 + entry] = Bv;
    Bv = dS * Bv + d * chunkA[(base + c) * 36 + entry];
  }
}

// score(t) = d^tl * (u^T B u) + sum_{s<tl} d^(tl-s) (u.w_s)^2

__global__ __launch_bounds__(128) void scanB_kernel(const float* __restrict__ Jw,
                                                    const float* __restrict__ Jr,
                                                    const float* __restrict__ rd,
                                                    const float* __restrict__ Bst,
                                                    const float* __restrict__ decay_logits,
                                                    float* __restrict__ score_w,
                                                    float* __restrict__ score_r) {
  int blk = blockIdx.x;
  int chunk = blk & 15, bh = (blk >> 4) & 31, type = blk >> 9;
  int tl = threadIdx.x;
  size_t tb = ((size_t)bh * Tt + chunk * 128) * 6;
  const float* U = (type == 0 ? rd : Jw) + tb;
  const float* W = (type == 0 ? Jw : Jr) + tb;
  __shared__ float wv[768];
  __shared__ float Bm[36];
  for (int i = tl; i < 768; i += 128) wv[i] = W[i];
  if (tl < 36) Bm[tl] = Bst[((size_t)(type * 32 + bh) * 16 + chunk) * 36 + tl];
  __syncthreads();
  float d = sigm(decay_logits[bh & 15]);
  float u[6];
#pragma unroll
  for (int i = 0; i < 6; i++) u[i] = U[tl * 6 + i];
  float q = 0.f;
#pragma unroll
  for (int i = 0; i < 6; i++) {
    float bi = 0.f;
#pragma unroll
    for (int j = 0; j < 6; j++) bi += Bm[i * 6 + j] * u[j];
    q += u[i] * bi;
  }
  float acc = 0.f;
  for (int s = 0; s < tl; s++) {
    const float* ws = &wv[s * 6];
    float dot = u[0]*ws[0] + u[1]*ws[1] + u[2]*ws[2] + u[3]*ws[3] + u[4]*ws[4] + u[5]*ws[5];
    acc = d * (acc + dot * dot);
  }
  float score = acc + powf(d, (float)tl) * q;
  float* outp = (type == 0 ? score_w : score_r);
  outp[(size_t)bh * Tt + chunk * 128 + tl] = score;
}

// ---------------- gate + combine (+ key-split partial reduction) ----------------

__global__ __launch_bounds__(256) void combine_kernel(const unsigned short* __restrict__ po,
                                                      const float* __restrict__ pll,
                                                      const unsigned short* __restrict__ Cq,
                                                      const float* __restrict__ score_w,
                                                      const float* __restrict__ score_r,
                                                      const float* __restrict__ mem_scale,
                                                      const float* __restrict__ rw_mix,
                                                      unsigned short* __restrict__ fused) {
  __shared__ float tmp[16], invl[16];
  int rowi = blockIdx.x;
  int b = rowi >> 11, t = rowi & 2047;
  bool two = (t >= 1024);
  float alpha = sigm(rw_mix[0]);
  if (threadIdx.x < 16) {
    int h = threadIdx.x;
    int bh = b * 16 + h;
    float l = pll[(size_t)bh * Tt + t];
    if (two) l += pll[(size_t)(32 + bh) * Tt + t];
    invl[h] = 1.f / l;
    size_t sh = (size_t)bh * Tt + t;
    float ms = (1.f - alpha) * score_w[sh] + alpha * score_r[sh];
    float gate = sigm(bf2f(Cq[(size_t)rowi * LDC + 3328 + h]));
    tmp[h] = sigm(ms * mem_scale[h]) * gate;
  }
  __syncthreads();
  float g = 0.f;
#pragma unroll
  for (int h = 0; h < 16; h++) g += tmp[h];
  g *= (1.f / 16.f);
  for (int d = threadIdx.x; d < Dd; d += 256) {
    float ov = bf2f(po[((size_t)b * Tt + t) * Dd + d]);
    if (two) ov += bf2f(po[((size_t)(2 + b) * Tt + t) * Dd + d]);
    float sv = ov * invl[d >> 6];
    float mv = bf2f(Cq[(size_t)rowi * LDC + 3392 + d]);
    fused[(size_t)rowi * Dd + d] = f2bf(sv + g * mv);
  }
}

// ---------------- launch ----------------

extern "C" void kernel_launch(void* const* d_in, const int* in_sizes, int n_in,
                              void* d_out, int out_size, void* d_ws, size_t ws_size,
                              hipStream_t stream) {
  (void)in_sizes; (void)n_in; (void)out_size; (void)ws_size;
  const float* x         = (const float*)d_in[0];
  const float* qkv_w     = (const float*)d_in[1];
  const float* qkv_b     = (const float*)d_in[2];
  const float* w1w       = (const float*)d_in[3];
  const float* w2w       = (const float*)d_in[4];
  const float* w1r       = (const float*)d_in[5];
  const float* w2r       = (const float*)d_in[6];
  const float* memv_w    = (const float*)d_in[7];
  const float* memv_b    = (const float*)d_in[8];
  const float* memg_w    = (const float*)d_in[9];
  const float* memg_b    = (const float*)d_in[10];
  const float* mem_scale = (const float*)d_in[11];
  const float* rw_mix    = (const float*)d_in[12];
  const float* out_w     = (const float*)d_in[13];
  const float* out_b     = (const float*)d_in[14];
  const float* decay_l   = (const float*)d_in[15];

  char* w = (char*)d_ws;
  unsigned short* xb    = (unsigned short*)(w + 0);          //  8388608
  unsigned short* Kc    = (unsigned short*)(w + 0);          //  overlay (xb dead after gemm)
  unsigned short* WT    = (unsigned short*)(w + 8388608);    //  9175040
  unsigned short* Vt    = (unsigned short*)(w + 8388608);    //  overlay (WT dead after gemm), f16
  unsigned short* outT  = (unsigned short*)(w + 17563648);   //  2097152
  float*          biasC = (float*)(w + 19660800);            //    17920
  unsigned short* Cbuf  = (unsigned short*)(w + 19678720);   // 36700160
  unsigned short* po    = (unsigned short*)(w + 56378880);   // 16777216  (4,2048,1024) bf16
  float*          pll   = (float*)(w + 73156096);            //   524288  (2,32,2048) fp32
  float*          Jw    = (float*)(w + 73680384);            //  1572864
  float*          Jr    = (float*)(w + 75253248);            //  1572864
  float*          rd    = (float*)(w + 76826112);            //  1572864
  float*          chA   = (float*)(w + 78398976);            //   147456
  float*          Bst   = (float*)(w + 78546432);            //   147456
  float*          sw    = (float*)(w + 78693888);            //   262144
  float*          sr    = (float*)(w + 78956032);            //   262144
  unsigned short* fused = (unsigned short*)(w + 79218176);   //  8388608

  cast_x_kernel<<<4096, 256, 0, stream>>>(x, xb);
  build_wt_kernel<<<dim3(140, 32), 256, 0, stream>>>(qkv_w, w1w, w2w, w1r, w2r,
                                                     memg_w, memv_w, WT);
  transpose_cast_kernel<<<dim3(32, 32), 256, 0, stream>>>(out_w, 1024, outT);
  bias_fill_kernel<<<18, 256, 0, stream>>>(qkv_b, memg_b, memv_b, biasC);

  gemm_kernel<true><<<dim3(35, 32), 256, 0, stream>>>(xb, WT, Cbuf, biasC, 4096, 4480, 1024);

  repack_kernel<<<1024, 256, 0, stream>>>(Cbuf, Kc, Vt);
  attn_kernel<<<dim3(32, 32), 256, 0, stream>>>(Cbuf, Kc, Vt, po, pll);
  lines_kernel<<<256, 256, 0, stream>>>(Cbuf, Jw, Jr, rd);
  scanA_kernel<<<1024, 64, 0, stream>>>(Jw, Jr, decay_l, chA);
  scanA2_kernel<<<9, 256, 0, stream>>>(chA, decay_l, Bst);
  scanB_kernel<<<1024, 128, 0, stream>>>(Jw, Jr, rd, Bst, decay_l, sw, sr);
  combine_kernel<<<4096, 256, 0, stream>>>(po, pll, Cbuf, sw, sr, mem_scale, rw_mix, fused);

  gemm_kernel<false><<<dim3(8, 32), 256, 0, stream>>>(fused, outT, d_out, out_b, 4096, 1024, 1024);
}

// Round 6
// 302.440 us; speedup vs baseline: 1.3945x; 1.3945x over previous
//
#include <hip/hip_runtime.h>

#define Bb 2
#define Tt 2048
#define Dd 1024
#define Hh 16
#define LDC 4480

typedef __attribute__((ext_vector_type(8))) short s16x8;
typedef __attribute__((ext_vector_type(4))) float f32x4;
typedef __attribute__((ext_vector_type(8))) _Float16 f16x8;

__device__ __forceinline__ float bf2f(unsigned short u) {
  unsigned v = ((unsigned)u) << 16;
  union { unsigned u; float f; } c; c.u = v; return c.f;
}
__device__ __forceinline__ unsigned short f2bf(float f) {
  union { float f; unsigned u; } c; c.f = f;
  unsigned u = c.u + 0x7fffu + ((c.u >> 16) & 1u);
  return (unsigned short)(u >> 16);
}
__device__ __forceinline__ float sigm(float x) { return 1.f / (1.f + expf(-x)); }

__device__ __forceinline__ void async_copy16(void* lds, const void* g) {
  __builtin_amdgcn_global_load_lds(
      (const __attribute__((address_space(1))) unsigned int*)g,
      (__attribute__((address_space(3))) unsigned int*)lds, 16, 0, 0);
}

// ---------------- cast x to bf16 ----------------

__global__ __launch_bounds__(256) void cast_x_kernel(const float* __restrict__ x,
                                                     unsigned short* __restrict__ xb) {
  int i = blockIdx.x * 256 + threadIdx.x;
  const float4* xv = reinterpret_cast<const float4*>(x);
  float4 v = xv[i];
  unsigned long long pk = (unsigned long long)f2bf(v.x)
                        | ((unsigned long long)f2bf(v.y) << 16)
                        | ((unsigned long long)f2bf(v.z) << 32)
                        | ((unsigned long long)f2bf(v.w) << 48);
  reinterpret_cast<unsigned long long*>(xb)[i] = pk;
}

// ---------------- fused weight concat + transpose + cast ----------------

__global__ __launch_bounds__(256) void build_wt_kernel(const float* __restrict__ qkv_w,
                                                       const float* __restrict__ w1w,
                                                       const float* __restrict__ w2w,
                                                       const float* __restrict__ w1r,
                                                       const float* __restrict__ w2r,
                                                       const float* __restrict__ memg_w,
                                                       const float* __restrict__ memv_w,
                                                       unsigned short* __restrict__ WT) {
  __shared__ float tile[32][33];
  int n0 = blockIdx.x * 32, k0 = blockIdx.y * 32;
  int tx = threadIdx.x & 31, ty = threadIdx.x >> 5;
#pragma unroll
  for (int i = 0; i < 4; i++) {
    int k = k0 + ty + i * 8, n = n0 + tx;
    float v;
    if (n < 3072)       v = qkv_w[(size_t)k * 3072 + n];
    else if (n < 3136)  v = w1w[k * 64 + (n - 3072)];
    else if (n < 3200)  v = w2w[k * 64 + (n - 3136)];
    else if (n < 3264)  v = w1r[k * 64 + (n - 3200)];
    else if (n < 3328)  v = w2r[k * 64 + (n - 3264)];
    else if (n < 3344)  v = memg_w[k * 16 + (n - 3328)];
    else if (n < 3392)  v = 0.f;
    else if (n < 4416)  v = memv_w[(size_t)k * 1024 + (n - 3392)];
    else                v = 0.f;
    tile[ty + i * 8][tx] = v;
  }
  __syncthreads();
#pragma unroll
  for (int i = 0; i < 4; i++) {
    int n = n0 + ty + i * 8, k = k0 + tx;
    WT[(size_t)n * 1024 + k] = f2bf(tile[tx][ty + i * 8]);
  }
}

// src: (1024, ncols) fp32 row-major -> dst: (ncols, 1024) bf16 row-major
__global__ __launch_bounds__(256) void transpose_cast_kernel(const float* __restrict__ src,
                                                             int ncols,
                                                             unsigned short* __restrict__ dst) {
  __shared__ float tile[32][33];
  int n0 = blockIdx.x * 32, k0 = blockIdx.y * 32;
  int tx = threadIdx.x & 31, ty = threadIdx.x >> 5;
#pragma unroll
  for (int i = 0; i < 4; i++) {
    int k = k0 + ty + i * 8, n = n0 + tx;
    tile[ty + i * 8][tx] = (n < ncols) ? src[(size_t)k * ncols + n] : 0.f;
  }
  __syncthreads();
#pragma unroll
  for (int i = 0; i < 4; i++) {
    int n = n0 + ty + i * 8, k = k0 + tx;
    if (n < ncols) dst[(size_t)n * 1024 + k] = f2bf(tile[tx][ty + i * 8]);
  }
}

__global__ void bias_fill_kernel(const float* __restrict__ qkv_b,
                                 const float* __restrict__ memg_b,
                                 const float* __restrict__ memv_b,
                                 float* __restrict__ bias) {
  int i = blockIdx.x * 256 + threadIdx.x;
  if (i >= LDC) return;
  float v = 0.f;
  if (i < 3072) v = qkv_b[i];
  else if (i >= 3328 && i < 3344) v = memg_b[i - 3328];
  else if (i >= 3392 && i < 4416) v = memv_b[i - 3392];
  bias[i] = v;
}

// ---------------- bf16 MFMA GEMM: C(M,N) = A(M,K) * B^T(N,K) + bias ----------------

template <bool OUT_BF16>
__global__ __launch_bounds__(256) void gemm_kernel(const unsigned short* __restrict__ A,
                                                   const unsigned short* __restrict__ Bt,
                                                   void* __restrict__ Cout,
                                                   const float* __restrict__ bias,
                                                   int M, int N, int K) {
  __shared__ unsigned short As[128 * 32];
  __shared__ unsigned short Bs[128 * 32];
  const int tid = threadIdx.x;
  const int lane = tid & 63, wid = tid >> 6;
  const int quad = lane >> 4, c16 = lane & 15;
  const int mBase = blockIdx.y * 128, nBase = blockIdx.x * 128;
  const int wm = wid >> 1, wn = wid & 1;
  const int srow = lane >> 2, scol = (lane & 3) << 3;

  f32x4 acc[4][4] = {};
  for (int k0 = 0; k0 < K; k0 += 32) {
    __syncthreads();
#pragma unroll
    for (int j = 0; j < 2; j++) {
      int rr = wid * 32 + j * 16;
      async_copy16(&As[rr * 32], &A[(size_t)(mBase + rr + srow) * K + k0 + scol]);
      async_copy16(&Bs[rr * 32], &Bt[(size_t)(nBase + rr + srow) * K + k0 + scol]);
    }
    __syncthreads();
    s16x8 af[4], bf[4];
#pragma unroll
    for (int mt = 0; mt < 4; mt++)
      af[mt] = *(const s16x8*)&As[(wm * 64 + mt * 16 + c16) * 32 + quad * 8];
#pragma unroll
    for (int nt = 0; nt < 4; nt++)
      bf[nt] = *(const s16x8*)&Bs[(wn * 64 + nt * 16 + c16) * 32 + quad * 8];
#pragma unroll
    for (int mt = 0; mt < 4; mt++)
#pragma unroll
      for (int nt = 0; nt < 4; nt++)
        acc[mt][nt] = __builtin_amdgcn_mfma_f32_16x16x32_bf16(af[mt], bf[nt], acc[mt][nt], 0, 0, 0);
  }
#pragma unroll
  for (int mt = 0; mt < 4; mt++)
#pragma unroll
    for (int nt = 0; nt < 4; nt++) {
      int col = nBase + wn * 64 + nt * 16 + c16;
      float bv = bias[col];
#pragma unroll
      for (int r = 0; r < 4; r++) {
        int row = mBase + wm * 64 + mt * 16 + quad * 4 + r;
        float v = acc[mt][nt][r] + bv;
        if (OUT_BF16)
          ((unsigned short*)Cout)[(size_t)row * N + col] = f2bf(v);
        else
          ((float*)Cout)[(size_t)row * N + col] = v;
      }
    }
}

// ---------------- repack K/V into staging-ready swizzled 4KB tiles ----------------
// K tile (bh,kb): 32 keys x 64 dims bf16. Chunk (key,p) [16B] holds dims
//   dg = p ^ (key&7), dg*8..+8  -> LDS ds_read_b128 of fragment is 2-way max.
// V tile (bh,kb): 64 dims x 32 perm-keys f16. Row d, chunk position
//   p = cq ^ ((d>>2)&3); chunk content e=0..7: k' = cq*8+e maps to original
//   key = (e>>2)*16 + cq*4 + (e&3)  (k-permutation shared with the P operand).

__global__ __launch_bounds__(256) void repack_kernel(const unsigned short* __restrict__ Cq,
                                                     unsigned short* __restrict__ Kt,
                                                     unsigned short* __restrict__ Vt) {
  int kb = blockIdx.x & 63, bh = blockIdx.x >> 6;
  int b = bh >> 4, h = bh & 15;
  int tid = threadIdx.x;
  size_t tbase = ((size_t)bh * 64 + kb) * 2048;
  // K direct
  {
    int key = tid >> 3, p = tid & 7, dg = p ^ (key & 7);
    size_t src = (size_t)(b * Tt + kb * 32 + key) * LDC + 1024 + h * 64 + dg * 8;
    s16x8 kv = *(const s16x8*)&Cq[src];
    *(s16x8*)&Kt[tbase + (size_t)tid * 8] = kv;
  }
  // V via LDS transpose (+f16 convert)
  __shared__ unsigned short vt[32 * 66];
  {
    int row = tid >> 3, c = tid & 7;
    size_t src = (size_t)(b * Tt + kb * 32 + row) * LDC + 2048 + h * 64 + c * 8;
    s16x8 vv = *(const s16x8*)&Cq[src];
#pragma unroll
    for (int e = 0; e < 8; e++) {
      union { _Float16 hf; unsigned short s; } cv;
      cv.hf = (_Float16)bf2f((unsigned short)vv[e]);
      vt[row * 66 + c * 8 + e] = cv.s;
    }
  }
  __syncthreads();
  {
    int d = tid >> 2, p = tid & 3, cq = p ^ ((d >> 2) & 3);
    s16x8 out;
#pragma unroll
    for (int e = 0; e < 8; e++) {
      int key = ((e >> 2) & 1) * 16 + cq * 4 + (e & 3);
      out[e] = (short)vt[key * 66 + d];
    }
    *(s16x8*)&Vt[tbase + (size_t)tid * 8] = out;
  }
}

// ---------------- block-cooperative MFMA flash attention ----------------
// Block = 4 waves, one bh, shared key walk through LDS-staged K/V tiles.
// Wave w owns paired q-tiles pi=g*4+w and 127-pi (balanced). Fixed-max
// softmax (scores tiny). S^T = K*Q^T; the two C-tiles pack directly into the
// f16 A-operand of one 16x16x32 PV MFMA via a k-permutation baked into Vt.

__device__ __forceinline__ void do_tile(int ks, int q0, int quad, int c16,
                                        const s16x8& qf0, const s16x8& qf1,
                                        const s16x8 kf[2][2], const f16x8 vb[4],
                                        float& l_i, f32x4 o[4]) {
  f32x4 st0 = {}, st1 = {};
  st0 = __builtin_amdgcn_mfma_f32_16x16x32_bf16(kf[0][0], qf0, st0, 0, 0, 0);
  st0 = __builtin_amdgcn_mfma_f32_16x16x32_bf16(kf[0][1], qf1, st0, 0, 0, 0);
  st1 = __builtin_amdgcn_mfma_f32_16x16x32_bf16(kf[1][0], qf0, st1, 0, 0, 0);
  st1 = __builtin_amdgcn_mfma_f32_16x16x32_bf16(kf[1][1], qf1, st1, 0, 0, 0);
  bool need_mask = (ks + 31 > q0);
  f16x8 pa;
  float lp = 0.f;
#pragma unroll
  for (int r = 0; r < 4; r++) {
    float v0 = st0[r] * 0.125f;
    float v1 = st1[r] * 0.125f;
    if (need_mask) {
      v0 = (ks + quad * 4 + r      <= q0 + c16) ? v0 : -1e30f;
      v1 = (ks + 16 + quad * 4 + r <= q0 + c16) ? v1 : -1e30f;
    }
    float p0 = __expf(v0);
    float p1 = __expf(v1);
    lp += p0 + p1;
    pa[r]     = (_Float16)p0;
    pa[4 + r] = (_Float16)p1;
  }
  l_i += lp;
#pragma unroll
  for (int nt = 0; nt < 4; nt++)
    o[nt] = __builtin_amdgcn_mfma_f32_16x16x32_f16(pa, vb[nt], o[nt], 0, 0, 0);
}

__global__ __launch_bounds__(256) void attn_kernel(const unsigned short* __restrict__ Cq,
                                                   const unsigned short* __restrict__ Kt,
                                                   const unsigned short* __restrict__ Vt,
                                                   unsigned short* __restrict__ po) {
  __shared__ unsigned short Kl[2048];
  __shared__ unsigned short Vl[2048];
  const int g0 = blockIdx.x, bh = blockIdx.y;
  const int g = ((bh >> 4) & 1) ? (15 - g0) : g0;  // makespan pairing heuristic
  const int b = bh >> 4, h = bh & 15;
  const int w = threadIdx.x >> 6, lane = threadIdx.x & 63;
  const int quad = lane >> 4, c16 = lane & 15;
  const int pi = g * 4 + w;
  const int qA = pi * 16, qB = 2032 - pi * 16;
  const int nkA = qA + 16, nkB = 2048 - pi * 16;
  const int bound = 2048 - 64 * g;
  const unsigned short* Ktb = Kt + (size_t)bh * 64 * 2048;
  const unsigned short* Vtb = Vt + (size_t)bh * 64 * 2048;
  const int ci = threadIdx.x;  // staging chunk 0..255

  size_t rowA = (size_t)(b * Tt + qA + c16) * LDC + h * 64;
  size_t rowB = (size_t)(b * Tt + qB + c16) * LDC + h * 64;
  s16x8 qA0 = *(const s16x8*)&Cq[rowA + quad * 8];
  s16x8 qA1 = *(const s16x8*)&Cq[rowA + 32 + quad * 8];
  s16x8 qB0 = *(const s16x8*)&Cq[rowB + quad * 8];
  s16x8 qB1 = *(const s16x8*)&Cq[rowB + 32 + quad * 8];

  float lA = 0.f, lB = 0.f;
  f32x4 oA[4] = {}, oB[4] = {};

  // initial stage (tile kb=0)
  {
    s16x8 k0 = *(const s16x8*)&Ktb[(size_t)ci * 8];
    s16x8 v0 = *(const s16x8*)&Vtb[(size_t)ci * 8];
    *(s16x8*)&Kl[ci * 8] = k0;
    *(s16x8*)&Vl[ci * 8] = v0;
  }
  __syncthreads();

  for (int ks = 0; ks < bound; ks += 32) {
    bool more = (ks + 32) < bound;
    s16x8 kreg, vreg;
    if (more) {
      size_t nb = ((size_t)(ks >> 5) + 1) * 2048 + (size_t)ci * 8;
      kreg = *(const s16x8*)&Ktb[nb];
      vreg = *(const s16x8*)&Vtb[nb];
    }
    if (ks < nkB) {
      s16x8 kf[2][2];
#pragma unroll
      for (int gg = 0; gg < 2; gg++)
#pragma unroll
        for (int half = 0; half < 2; half++) {
          int key = gg * 16 + c16;
          int p = (half * 4 + quad) ^ (c16 & 7);
          kf[gg][half] = *(const s16x8*)&Kl[(key * 8 + p) * 8];
        }
      f16x8 vb[4];
#pragma unroll
      for (int nt = 0; nt < 4; nt++) {
        int d = nt * 16 + c16;
        int p = quad ^ ((d >> 2) & 3);
        vb[nt] = *(const f16x8*)&Vl[(d * 4 + p) * 8];
      }
      do_tile(ks, qB, quad, c16, qB0, qB1, kf, vb, lB, oB);
      if (ks < nkA)
        do_tile(ks, qA, quad, c16, qA0, qA1, kf, vb, lA, oA);
    }
    __syncthreads();
    if (more) {
      *(s16x8*)&Kl[ci * 8] = kreg;
      *(s16x8*)&Vl[ci * 8] = vreg;
      __syncthreads();
    }
  }

  // reduce l over quads (lane holds partial for q=c16), then broadcast inverse
  lB += __shfl_xor(lB, 16, 64); lB += __shfl_xor(lB, 32, 64);
  lA += __shfl_xor(lA, 16, 64); lA += __shfl_xor(lA, 32, 64);
  float invB = 1.f / lB, invA = 1.f / lA;
#pragma unroll
  for (int r = 0; r < 4; r++) {
    float ivB = __shfl(invB, quad * 4 + r, 64);
    float ivA = __shfl(invA, quad * 4 + r, 64);
    size_t baseB = (size_t)(b * Tt + qB + quad * 4 + r) * Dd + h * 64;
    size_t baseA = (size_t)(b * Tt + qA + quad * 4 + r) * Dd + h * 64;
#pragma unroll
    for (int nt = 0; nt < 4; nt++) {
      po[baseB + nt * 16 + c16] = f2bf(oB[nt][r] * ivB);
      po[baseA + nt * 16 + c16] = f2bf(oA[nt][r] * ivA);
    }
  }
}

// ---------------- Plucker lines ----------------

__device__ __forceinline__ void ext6(const float* p, const float* q, float* L) {
  L[0] = p[0] * q[1] - p[1] * q[0];
  L[1] = p[0] * q[2] - p[2] * q[0];
  L[2] = p[0] * q[3] - p[3] * q[0];
  L[3] = p[1] * q[2] - p[2] * q[1];
  L[4] = p[1] * q[3] - p[3] * q[1];
  L[5] = p[2] * q[3] - p[3] * q[2];
  float n = sqrtf(L[0]*L[0] + L[1]*L[1] + L[2]*L[2] + L[3]*L[3] + L[4]*L[4] + L[5]*L[5]);
  float inv = 1.f / fmaxf(n, 1e-12f);
#pragma unroll
  for (int k = 0; k < 6; k++) L[k] *= inv;
}

__global__ void lines_kernel(const unsigned short* __restrict__ Cq,
                             float* __restrict__ Jw, float* __restrict__ Jr,
                             float* __restrict__ rd) {
  int idx = blockIdx.x * 256 + threadIdx.x;
  int h = idx & 15, t = (idx >> 4) & 2047, b = idx >> 15;
  size_t row = (size_t)(b * Tt + t) * LDC;
  float w1[4], w2[4], r1[4], r2[4];
#pragma unroll
  for (int k = 0; k < 4; k++) {
    w1[k] = (t > 0) ? bf2f(Cq[row - LDC + 3072 + h * 4 + k]) : 0.f;
    w2[k] = bf2f(Cq[row + 3136 + h * 4 + k]);
    r1[k] = bf2f(Cq[row + 3200 + h * 4 + k]);
    r2[k] = bf2f(Cq[row + 3264 + h * 4 + k]);
  }
  float Lw[6], Lr[6];
  ext6(w1, w2, Lw);
  ext6(r1, r2, Lr);
  size_t ob = ((size_t)(b * Hh + h) * Tt + t) * 6;
  Jw[ob + 0] = Lw[5]; Jw[ob + 1] = -Lw[4]; Jw[ob + 2] = Lw[3];
  Jw[ob + 3] = Lw[2]; Jw[ob + 4] = -Lw[1]; Jw[ob + 5] = Lw[0];
  Jr[ob + 0] = Lr[5]; Jr[ob + 1] = -Lr[4]; Jr[ob + 2] = Lr[3];
  Jr[ob + 3] = Lr[2]; Jr[ob + 4] = -Lr[1]; Jr[ob + 5] = Lr[0];
#pragma unroll
  for (int k = 0; k < 6; k++) rd[ob + k] = Lr[k];
}

// ---------------- chunked decay scan ----------------

__global__ __launch_bounds__(64) void scanA_kernel(const float* __restrict__ Jw,
                                                   const float* __restrict__ Jr,
                                                   const float* __restrict__ decay_logits,
                                                   float* __restrict__ chunkA) {
  int blk = blockIdx.x;
  int chunk = blk & 15, bh = (blk >> 4) & 31, type = blk >> 9;
  int lane = threadIdx.x;
  const float* V = (type == 0 ? Jw : Jr) + ((size_t)bh * Tt + chunk * 128) * 6;
  __shared__ float v[768];
  for (int i = lane; i < 768; i += 64) v[i] = V[i];
  __syncthreads();
  float d = sigm(decay_logits[bh & 15]);
  int ll = lane < 36 ? lane : 35;
  int i6 = ll / 6, j6 = ll % 6;
  float A = 0.f;
  for (int s = 0; s < 128; s++) A = d * A + v[s * 6 + i6] * v[s * 6 + j6];
  if (lane < 36) chunkA[((size_t)(type * 32 + bh) * 16 + chunk) * 36 + lane] = A;
}

__global__ void scanA2_kernel(const float* __restrict__ chunkA,
                              const float* __restrict__ decay_logits,
                              float* __restrict__ Bst) {
  int idx = blockIdx.x * 256 + threadIdx.x;
  if (idx >= 2 * 32 * 36) return;
  int entry = idx % 36, bh = (idx / 36) % 32, type = idx / (36 * 32);
  float d = sigm(decay_logits[bh & 15]);
  float dS = powf(d, 128.f);
  float Bv = 0.f;
  size_t base = (size_t)(type * 32 + bh) * 16;
  for (int c = 0; c < 16; c++) {
    Bst[(base + c) * 36 + entry] = Bv;
    Bv = dS * Bv + d * chunkA[(base + c) * 36 + entry];
  }
}

// score(t) = d^tl * (u^T B u) + sum_{s<tl} d^(tl-s) (u.w_s)^2

__global__ __launch_bounds__(128) void scanB_kernel(const float* __restrict__ Jw,
                                                    const float* __restrict__ Jr,
                                                    const float* __restrict__ rd,
                                                    const float* __restrict__ Bst,
                                                    const float* __restrict__ decay_logits,
                                                    float* __restrict__ score_w,
                                                    float* __restrict__ score_r) {
  int blk = blockIdx.x;
  int chunk = blk & 15, bh = (blk >> 4) & 31, type = blk >> 9;
  int tl = threadIdx.x;
  size_t tb = ((size_t)bh * Tt + chunk * 128) * 6;
  const float* U = (type == 0 ? rd : Jw) + tb;
  const float* W = (type == 0 ? Jw : Jr) + tb;
  __shared__ float wv[768];
  __shared__ float Bm[36];
  for (int i = tl; i < 768; i += 128) wv[i] = W[i];
  if (tl < 36) Bm[tl] = Bst[((size_t)(type * 32 + bh) * 16 + chunk) * 36 + tl];
  __syncthreads();
  float d = sigm(decay_logits[bh & 15]);
  float u[6];
#pragma unroll
  for (int i = 0; i < 6; i++) u[i] = U[tl * 6 + i];
  float q = 0.f;
#pragma unroll
  for (int i = 0; i < 6; i++) {
    float bi = 0.f;
#pragma unroll
    for (int j = 0; j < 6; j++) bi += Bm[i * 6 + j] * u[j];
    q += u[i] * bi;
  }
  float acc = 0.f;
  for (int s = 0; s < tl; s++) {
    const float* ws = &wv[s * 6];
    float dot = u[0]*ws[0] + u[1]*ws[1] + u[2]*ws[2] + u[3]*ws[3] + u[4]*ws[4] + u[5]*ws[5];
    acc = d * (acc + dot * dot);
  }
  float score = acc + powf(d, (float)tl) * q;
  float* outp = (type == 0 ? score_w : score_r);
  outp[(size_t)bh * Tt + chunk * 128 + tl] = score;
}

// ---------------- gate + combine ----------------

__global__ __launch_bounds__(256) void combine_kernel(const unsigned short* __restrict__ po,
                                                      const unsigned short* __restrict__ Cq,
                                                      const float* __restrict__ score_w,
                                                      const float* __restrict__ score_r,
                                                      const float* __restrict__ mem_scale,
                                                      const float* __restrict__ rw_mix,
                                                      unsigned short* __restrict__ fused) {
  __shared__ float tmp[16];
  int rowi = blockIdx.x;
  int b = rowi >> 11, t = rowi & 2047;
  float alpha = sigm(rw_mix[0]);
  if (threadIdx.x < 16) {
    int h = threadIdx.x;
    size_t sh = (size_t)(b * 16 + h) * Tt + t;
    float ms = (1.f - alpha) * score_w[sh] + alpha * score_r[sh];
    float gate = sigm(bf2f(Cq[(size_t)rowi * LDC + 3328 + h]));
    tmp[h] = sigm(ms * mem_scale[h]) * gate;
  }
  __syncthreads();
  float g = 0.f;
#pragma unroll
  for (int h = 0; h < 16; h++) g += tmp[h];
  g *= (1.f / 16.f);
  for (int d = threadIdx.x; d < Dd; d += 256) {
    float sv = bf2f(po[((size_t)b * Tt + t) * Dd + d]);
    float mv = bf2f(Cq[(size_t)rowi * LDC + 3392 + d]);
    fused[(size_t)rowi * Dd + d] = f2bf(sv + g * mv);
  }
}

// ---------------- launch ----------------

extern "C" void kernel_launch(void* const* d_in, const int* in_sizes, int n_in,
                              void* d_out, int out_size, void* d_ws, size_t ws_size,
                              hipStream_t stream) {
  (void)in_sizes; (void)n_in; (void)out_size; (void)ws_size;
  const float* x         = (const float*)d_in[0];
  const float* qkv_w     = (const float*)d_in[1];
  const float* qkv_b     = (const float*)d_in[2];
  const float* w1w       = (const float*)d_in[3];
  const float* w2w       = (const float*)d_in[4];
  const float* w1r       = (const float*)d_in[5];
  const float* w2r       = (const float*)d_in[6];
  const float* memv_w    = (const float*)d_in[7];
  const float* memv_b    = (const float*)d_in[8];
  const float* memg_w    = (const float*)d_in[9];
  const float* memg_b    = (const float*)d_in[10];
  const float* mem_scale = (const float*)d_in[11];
  const float* rw_mix    = (const float*)d_in[12];
  const float* out_w     = (const float*)d_in[13];
  const float* out_b     = (const float*)d_in[14];
  const float* decay_l   = (const float*)d_in[15];

  char* w = (char*)d_ws;
  unsigned short* xb    = (unsigned short*)(w + 0);          //  8388608
  unsigned short* Kt    = (unsigned short*)(w + 0);          //  8388608 overlay (xb dead after gemm)
  unsigned short* WT    = (unsigned short*)(w + 8388608);    //  9175040
  unsigned short* Vt    = (unsigned short*)(w + 8388608);    //  8388608 overlay (WT dead after gemm)
  unsigned short* outT  = (unsigned short*)(w + 17563648);   //  2097152
  float*          biasC = (float*)(w + 19660800);            //    17920
  unsigned short* Cbuf  = (unsigned short*)(w + 19678720);   // 36700160
  unsigned short* po    = (unsigned short*)(w + 56378880);   //  8388608  (2,2048,1024) bf16
  float*          Jw    = (float*)(w + 73680384);            //  1572864
  float*          Jr    = (float*)(w + 75253248);            //  1572864
  float*          rd    = (float*)(w + 76826112);            //  1572864
  float*          chA   = (float*)(w + 78398976);            //   147456
  float*          Bst   = (float*)(w + 78546432);            //   147456
  float*          sw    = (float*)(w + 78693888);            //   262144
  float*          sr    = (float*)(w + 78956032);            //   262144
  unsigned short* fused = (unsigned short*)(w + 79218176);   //  8388608

  cast_x_kernel<<<4096, 256, 0, stream>>>(x, xb);
  build_wt_kernel<<<dim3(140, 32), 256, 0, stream>>>(qkv_w, w1w, w2w, w1r, w2r,
                                                     memg_w, memv_w, WT);
  transpose_cast_kernel<<<dim3(32, 32), 256, 0, stream>>>(out_w, 1024, outT);
  bias_fill_kernel<<<18, 256, 0, stream>>>(qkv_b, memg_b, memv_b, biasC);

  gemm_kernel<true><<<dim3(35, 32), 256, 0, stream>>>(xb, WT, Cbuf, biasC, 4096, 4480, 1024);

  repack_kernel<<<2048, 256, 0, stream>>>(Cbuf, Kt, Vt);
  attn_kernel<<<dim3(16, 32), 256, 0, stream>>>(Cbuf, Kt, Vt, po);
  lines_kernel<<<256, 256, 0, stream>>>(Cbuf, Jw, Jr, rd);
  scanA_kernel<<<1024, 64, 0, stream>>>(Jw, Jr, decay_l, chA);
  scanA2_kernel<<<9, 256, 0, stream>>>(chA, decay_l, Bst);
  scanB_kernel<<<1024, 128, 0, stream>>>(Jw, Jr, rd, Bst, decay_l, sw, sr);
  combine_kernel<<<4096, 256, 0, stream>>>(po, Cbuf, sw, sr, mem_scale, rw_mix, fused);

  gemm_kernel<false><<<dim3(8, 32), 256, 0, stream>>>(fused, outT, d_out, out_b, 4096, 1024, 1024);
}

// Round 7
// 299.386 us; speedup vs baseline: 1.4088x; 1.0102x over previous
//
#include <hip/hip_runtime.h>

#define Bb 2
#define Tt 2048
#define Dd 1024
#define Hh 16
#define LDC 4480

typedef __attribute__((ext_vector_type(8))) short s16x8;
typedef __attribute__((ext_vector_type(4))) float f32x4;
typedef __attribute__((ext_vector_type(8))) _Float16 f16x8;

__device__ __forceinline__ float bf2f(unsigned short u) {
  unsigned v = ((unsigned)u) << 16;
  union { unsigned u; float f; } c; c.u = v; return c.f;
}
__device__ __forceinline__ unsigned short f2bf(float f) {
  union { float f; unsigned u; } c; c.f = f;
  unsigned u = c.u + 0x7fffu + ((c.u >> 16) & 1u);
  return (unsigned short)(u >> 16);
}
__device__ __forceinline__ float sigm(float x) { return 1.f / (1.f + expf(-x)); }

// XOR chunk swizzle baked into GEMM operand buffers: 16B chunk q of row r
// lives at slot q ^ ((r>>1)&3). Makes gemm fragment ds_read_b128 2-way max.
__device__ __forceinline__ int swz(int row, int k) {
  return (k & ~31) | (k & 7) | (((((k >> 3) & 3) ^ ((row >> 1) & 3))) << 3);
}

__device__ __forceinline__ void async_copy16(void* lds, const void* g) {
  __builtin_amdgcn_global_load_lds(
      (const __attribute__((address_space(1))) unsigned int*)g,
      (__attribute__((address_space(3))) unsigned int*)lds, 16, 0, 0);
}

// ---------------- cast x to bf16 (swizzled layout) ----------------

__global__ __launch_bounds__(256) void cast_x_kernel(const float* __restrict__ x,
                                                     unsigned short* __restrict__ xb) {
  int i = blockIdx.x * 256 + threadIdx.x;       // one 16B chunk (8 floats) per thread
  int row = i >> 7;                              // 128 chunks per 1024-col row
  int colbase = (i & 127) * 8;
  const float4* xv = reinterpret_cast<const float4*>(x + (size_t)i * 8);
  float4 a = xv[0], b = xv[1];
  s16x8 out;
  out[0] = (short)f2bf(a.x); out[1] = (short)f2bf(a.y);
  out[2] = (short)f2bf(a.z); out[3] = (short)f2bf(a.w);
  out[4] = (short)f2bf(b.x); out[5] = (short)f2bf(b.y);
  out[6] = (short)f2bf(b.z); out[7] = (short)f2bf(b.w);
  *(s16x8*)&xb[(size_t)row * 1024 + swz(row, colbase)] = out;
}

// ---------------- fused weight concat + transpose + cast (swizzled) ----------------

__global__ __launch_bounds__(256) void build_wt_kernel(const float* __restrict__ qkv_w,
                                                       const float* __restrict__ w1w,
                                                       const float* __restrict__ w2w,
                                                       const float* __restrict__ w1r,
                                                       const float* __restrict__ w2r,
                                                       const float* __restrict__ memg_w,
                                                       const float* __restrict__ memv_w,
                                                       unsigned short* __restrict__ WT) {
  __shared__ float tile[32][33];
  int n0 = blockIdx.x * 32, k0 = blockIdx.y * 32;
  int tx = threadIdx.x & 31, ty = threadIdx.x >> 5;
#pragma unroll
  for (int i = 0; i < 4; i++) {
    int k = k0 + ty + i * 8, n = n0 + tx;
    float v;
    if (n < 3072)       v = qkv_w[(size_t)k * 3072 + n];
    else if (n < 3136)  v = w1w[k * 64 + (n - 3072)];
    else if (n < 3200)  v = w2w[k * 64 + (n - 3136)];
    else if (n < 3264)  v = w1r[k * 64 + (n - 3200)];
    else if (n < 3328)  v = w2r[k * 64 + (n - 3264)];
    else if (n < 3344)  v = memg_w[k * 16 + (n - 3328)];
    else if (n < 3392)  v = 0.f;
    else if (n < 4416)  v = memv_w[(size_t)k * 1024 + (n - 3392)];
    else                v = 0.f;
    tile[ty + i * 8][tx] = v;
  }
  __syncthreads();
#pragma unroll
  for (int i = 0; i < 4; i++) {
    int n = n0 + ty + i * 8, k = k0 + tx;
    WT[(size_t)n * 1024 + swz(n, k)] = f2bf(tile[tx][ty + i * 8]);
  }
}

// src: (1024, ncols) fp32 -> dst: (ncols, 1024) bf16, swizzled
__global__ __launch_bounds__(256) void transpose_cast_kernel(const float* __restrict__ src,
                                                             int ncols,
                                                             unsigned short* __restrict__ dst) {
  __shared__ float tile[32][33];
  int n0 = blockIdx.x * 32, k0 = blockIdx.y * 32;
  int tx = threadIdx.x & 31, ty = threadIdx.x >> 5;
#pragma unroll
  for (int i = 0; i < 4; i++) {
    int k = k0 + ty + i * 8, n = n0 + tx;
    tile[ty + i * 8][tx] = (n < ncols) ? src[(size_t)k * ncols + n] : 0.f;
  }
  __syncthreads();
#pragma unroll
  for (int i = 0; i < 4; i++) {
    int n = n0 + ty + i * 8, k = k0 + tx;
    if (n < ncols) dst[(size_t)n * 1024 + swz(n, k)] = f2bf(tile[tx][ty + i * 8]);
  }
}

__global__ void bias_fill_kernel(const float* __restrict__ qkv_b,
                                 const float* __restrict__ memg_b,
                                 const float* __restrict__ memv_b,
                                 float* __restrict__ bias) {
  int i = blockIdx.x * 256 + threadIdx.x;
  if (i >= LDC) return;
  float v = 0.f;
  if (i < 3072) v = qkv_b[i];
  else if (i >= 3328 && i < 3344) v = memg_b[i - 3328];
  else if (i >= 3392 && i < 4416) v = memv_b[i - 3392];
  bias[i] = v;
}

// ---------------- bf16 MFMA GEMM (swizzled operands) ----------------

template <bool OUT_BF16>
__global__ __launch_bounds__(256) void gemm_kernel(const unsigned short* __restrict__ A,
                                                   const unsigned short* __restrict__ Bt,
                                                   void* __restrict__ Cout,
                                                   const float* __restrict__ bias,
                                                   int M, int N, int K) {
  __shared__ unsigned short As[128 * 32];
  __shared__ unsigned short Bs[128 * 32];
  const int tid = threadIdx.x;
  const int lane = tid & 63, wid = tid >> 6;
  const int quad = lane >> 4, c16 = lane & 15;
  const int mBase = blockIdx.y * 128, nBase = blockIdx.x * 128;
  const int wm = wid >> 1, wn = wid & 1;
  const int srow = lane >> 2, scol = (lane & 3) << 3;
  const int slot = (quad ^ ((c16 >> 1) & 3)) * 8;  // de-swizzle for fragment reads

  f32x4 acc[4][4] = {};
  for (int k0 = 0; k0 < K; k0 += 32) {
    __syncthreads();
#pragma unroll
    for (int j = 0; j < 2; j++) {
      int rr = wid * 32 + j * 16;
      async_copy16(&As[rr * 32], &A[(size_t)(mBase + rr + srow) * K + k0 + scol]);
      async_copy16(&Bs[rr * 32], &Bt[(size_t)(nBase + rr + srow) * K + k0 + scol]);
    }
    __syncthreads();
    s16x8 af[4], bf[4];
#pragma unroll
    for (int mt = 0; mt < 4; mt++)
      af[mt] = *(const s16x8*)&As[(wm * 64 + mt * 16 + c16) * 32 + slot];
#pragma unroll
    for (int nt = 0; nt < 4; nt++)
      bf[nt] = *(const s16x8*)&Bs[(wn * 64 + nt * 16 + c16) * 32 + slot];
#pragma unroll
    for (int mt = 0; mt < 4; mt++)
#pragma unroll
      for (int nt = 0; nt < 4; nt++)
        acc[mt][nt] = __builtin_amdgcn_mfma_f32_16x16x32_bf16(af[mt], bf[nt], acc[mt][nt], 0, 0, 0);
  }
#pragma unroll
  for (int mt = 0; mt < 4; mt++)
#pragma unroll
    for (int nt = 0; nt < 4; nt++) {
      int col = nBase + wn * 64 + nt * 16 + c16;
      float bv = bias[col];
#pragma unroll
      for (int r = 0; r < 4; r++) {
        int row = mBase + wm * 64 + mt * 16 + quad * 4 + r;
        float v = acc[mt][nt][r] + bv;
        if (OUT_BF16)
          ((unsigned short*)Cout)[(size_t)row * N + col] = f2bf(v);
        else
          ((float*)Cout)[(size_t)row * N + col] = v;
      }
    }
}

// ---------------- repack K/V into staging-ready swizzled 4KB tiles ----------------

__global__ __launch_bounds__(256) void repack_kernel(const unsigned short* __restrict__ Cq,
                                                     unsigned short* __restrict__ Kt,
                                                     unsigned short* __restrict__ Vt) {
  int kb = blockIdx.x & 63, bh = blockIdx.x >> 6;
  int b = bh >> 4, h = bh & 15;
  int tid = threadIdx.x;
  size_t tbase = ((size_t)bh * 64 + kb) * 2048;
  {
    int key = tid >> 3, p = tid & 7, dg = p ^ (key & 7);
    size_t src = (size_t)(b * Tt + kb * 32 + key) * LDC + 1024 + h * 64 + dg * 8;
    s16x8 kv = *(const s16x8*)&Cq[src];
    *(s16x8*)&Kt[tbase + (size_t)tid * 8] = kv;
  }
  __shared__ unsigned short vt[32 * 66];
  {
    int row = tid >> 3, c = tid & 7;
    size_t src = (size_t)(b * Tt + kb * 32 + row) * LDC + 2048 + h * 64 + c * 8;
    s16x8 vv = *(const s16x8*)&Cq[src];
#pragma unroll
    for (int e = 0; e < 8; e++) {
      union { _Float16 hf; unsigned short s; } cv;
      cv.hf = (_Float16)bf2f((unsigned short)vv[e]);
      vt[row * 66 + c * 8 + e] = cv.s;
    }
  }
  __syncthreads();
  {
    int d = tid >> 2, p = tid & 3, cq = p ^ ((d >> 2) & 3);
    s16x8 out;
#pragma unroll
    for (int e = 0; e < 8; e++) {
      int key = ((e >> 2) & 1) * 16 + cq * 4 + (e & 3);
      out[e] = (short)vt[key * 66 + d];
    }
    *(s16x8*)&Vt[tbase + (size_t)tid * 8] = out;
  }
}

// ---------------- block-cooperative MFMA flash attention ----------------

__device__ __forceinline__ void do_tile(int ks, int q0, int quad, int c16,
                                        const s16x8& qf0, const s16x8& qf1,
                                        const s16x8 kf[2][2], const f16x8 vb[4],
                                        float& l_i, f32x4 o[4]) {
  f32x4 st0 = {}, st1 = {};
  st0 = __builtin_amdgcn_mfma_f32_16x16x32_bf16(kf[0][0], qf0, st0, 0, 0, 0);
  st0 = __builtin_amdgcn_mfma_f32_16x16x32_bf16(kf[0][1], qf1, st0, 0, 0, 0);
  st1 = __builtin_amdgcn_mfma_f32_16x16x32_bf16(kf[1][0], qf0, st1, 0, 0, 0);
  st1 = __builtin_amdgcn_mfma_f32_16x16x32_bf16(kf[1][1], qf1, st1, 0, 0, 0);
  bool need_mask = (ks + 31 > q0);
  f16x8 pa;
  float lp = 0.f;
#pragma unroll
  for (int r = 0; r < 4; r++) {
    float v0 = st0[r] * 0.125f;
    float v1 = st1[r] * 0.125f;
    if (need_mask) {
      v0 = (ks + quad * 4 + r      <= q0 + c16) ? v0 : -1e30f;
      v1 = (ks + 16 + quad * 4 + r <= q0 + c16) ? v1 : -1e30f;
    }
    float p0 = __expf(v0);
    float p1 = __expf(v1);
    lp += p0 + p1;
    pa[r]     = (_Float16)p0;
    pa[4 + r] = (_Float16)p1;
  }
  l_i += lp;
#pragma unroll
  for (int nt = 0; nt < 4; nt++)
    o[nt] = __builtin_amdgcn_mfma_f32_16x16x32_f16(pa, vb[nt], o[nt], 0, 0, 0);
}

__global__ __launch_bounds__(256) void attn_kernel(const unsigned short* __restrict__ Cq,
                                                   const unsigned short* __restrict__ Kt,
                                                   const unsigned short* __restrict__ Vt,
                                                   unsigned short* __restrict__ po) {
  __shared__ unsigned short Kl[2048];
  __shared__ unsigned short Vl[2048];
  const int g0 = blockIdx.x, bh = blockIdx.y;
  const int g = ((bh >> 4) & 1) ? (15 - g0) : g0;
  const int b = bh >> 4, h = bh & 15;
  const int w = threadIdx.x >> 6, lane = threadIdx.x & 63;
  const int quad = lane >> 4, c16 = lane & 15;
  const int pi = g * 4 + w;
  const int qA = pi * 16, qB = 2032 - pi * 16;
  const int nkA = qA + 16, nkB = 2048 - pi * 16;
  const int bound = 2048 - 64 * g;
  const unsigned short* Ktb = Kt + (size_t)bh * 64 * 2048;
  const unsigned short* Vtb = Vt + (size_t)bh * 64 * 2048;
  const int ci = threadIdx.x;

  size_t rowA = (size_t)(b * Tt + qA + c16) * LDC + h * 64;
  size_t rowB = (size_t)(b * Tt + qB + c16) * LDC + h * 64;
  s16x8 qA0 = *(const s16x8*)&Cq[rowA + quad * 8];
  s16x8 qA1 = *(const s16x8*)&Cq[rowA + 32 + quad * 8];
  s16x8 qB0 = *(const s16x8*)&Cq[rowB + quad * 8];
  s16x8 qB1 = *(const s16x8*)&Cq[rowB + 32 + quad * 8];

  float lA = 0.f, lB = 0.f;
  f32x4 oA[4] = {}, oB[4] = {};

  {
    s16x8 k0 = *(const s16x8*)&Ktb[(size_t)ci * 8];
    s16x8 v0 = *(const s16x8*)&Vtb[(size_t)ci * 8];
    *(s16x8*)&Kl[ci * 8] = k0;
    *(s16x8*)&Vl[ci * 8] = v0;
  }
  __syncthreads();

  for (int ks = 0; ks < bound; ks += 32) {
    bool more = (ks + 32) < bound;
    s16x8 kreg, vreg;
    if (more) {
      size_t nb = ((size_t)(ks >> 5) + 1) * 2048 + (size_t)ci * 8;
      kreg = *(const s16x8*)&Ktb[nb];
      vreg = *(const s16x8*)&Vtb[nb];
    }
    if (ks < nkB) {
      s16x8 kf[2][2];
#pragma unroll
      for (int gg = 0; gg < 2; gg++)
#pragma unroll
        for (int half = 0; half < 2; half++) {
          int key = gg * 16 + c16;
          int p = (half * 4 + quad) ^ (c16 & 7);
          kf[gg][half] = *(const s16x8*)&Kl[(key * 8 + p) * 8];
        }
      f16x8 vb[4];
#pragma unroll
      for (int nt = 0; nt < 4; nt++) {
        int d = nt * 16 + c16;
        int p = quad ^ ((d >> 2) & 3);
        vb[nt] = *(const f16x8*)&Vl[(d * 4 + p) * 8];
      }
      do_tile(ks, qB, quad, c16, qB0, qB1, kf, vb, lB, oB);
      if (ks < nkA)
        do_tile(ks, qA, quad, c16, qA0, qA1, kf, vb, lA, oA);
    }
    __syncthreads();
    if (more) {
      *(s16x8*)&Kl[ci * 8] = kreg;
      *(s16x8*)&Vl[ci * 8] = vreg;
      __syncthreads();
    }
  }

  lB += __shfl_xor(lB, 16, 64); lB += __shfl_xor(lB, 32, 64);
  lA += __shfl_xor(lA, 16, 64); lA += __shfl_xor(lA, 32, 64);
  float invB = 1.f / lB, invA = 1.f / lA;
#pragma unroll
  for (int r = 0; r < 4; r++) {
    float ivB = __shfl(invB, quad * 4 + r, 64);
    float ivA = __shfl(invA, quad * 4 + r, 64);
    size_t baseB = (size_t)(b * Tt + qB + quad * 4 + r) * Dd + h * 64;
    size_t baseA = (size_t)(b * Tt + qA + quad * 4 + r) * Dd + h * 64;
#pragma unroll
    for (int nt = 0; nt < 4; nt++) {
      po[baseB + nt * 16 + c16] = f2bf(oB[nt][r] * ivB);
      po[baseA + nt * 16 + c16] = f2bf(oA[nt][r] * ivA);
    }
  }
}

// ---------------- Plucker lines ----------------

__device__ __forceinline__ void ext6(const float* p, const float* q, float* L) {
  L[0] = p[0] * q[1] - p[1] * q[0];
  L[1] = p[0] * q[2] - p[2] * q[0];
  L[2] = p[0] * q[3] - p[3] * q[0];
  L[3] = p[1] * q[2] - p[2] * q[1];
  L[4] = p[1] * q[3] - p[3] * q[1];
  L[5] = p[2] * q[3] - p[3] * q[2];
  float n = sqrtf(L[0]*L[0] + L[1]*L[1] + L[2]*L[2] + L[3]*L[3] + L[4]*L[4] + L[5]*L[5]);
  float inv = 1.f / fmaxf(n, 1e-12f);
#pragma unroll
  for (int k = 0; k < 6; k++) L[k] *= inv;
}

__global__ void lines_kernel(const unsigned short* __restrict__ Cq,
                             float* __restrict__ Jw, float* __restrict__ Jr,
                             float* __restrict__ rd) {
  int idx = blockIdx.x * 256 + threadIdx.x;
  int h = idx & 15, t = (idx >> 4) & 2047, b = idx >> 15;
  size_t row = (size_t)(b * Tt + t) * LDC;
  float w1[4], w2[4], r1[4], r2[4];
#pragma unroll
  for (int k = 0; k < 4; k++) {
    w1[k] = (t > 0) ? bf2f(Cq[row - LDC + 3072 + h * 4 + k]) : 0.f;
    w2[k] = bf2f(Cq[row + 3136 + h * 4 + k]);
    r1[k] = bf2f(Cq[row + 3200 + h * 4 + k]);
    r2[k] = bf2f(Cq[row + 3264 + h * 4 + k]);
  }
  float Lw[6], Lr[6];
  ext6(w1, w2, Lw);
  ext6(r1, r2, Lr);
  size_t ob = ((size_t)(b * Hh + h) * Tt + t) * 6;
  Jw[ob + 0] = Lw[5]; Jw[ob + 1] = -Lw[4]; Jw[ob + 2] = Lw[3];
  Jw[ob + 3] = Lw[2]; Jw[ob + 4] = -Lw[1]; Jw[ob + 5] = Lw[0];
  Jr[ob + 0] = Lr[5]; Jr[ob + 1] = -Lr[4]; Jr[ob + 2] = Lr[3];
  Jr[ob + 3] = Lr[2]; Jr[ob + 4] = -Lr[1]; Jr[ob + 5] = Lr[0];
#pragma unroll
  for (int k = 0; k < 6; k++) rd[ob + k] = Lr[k];
}

// ---------------- chunked decay scan ----------------

__global__ __launch_bounds__(64) void scanA_kernel(const float* __restrict__ Jw,
                                                   const float* __restrict__ Jr,
                                                   const float* __restrict__ decay_logits,
                                                   float* __restrict__ chunkA) {
  int blk = blockIdx.x;
  int chunk = blk & 15, bh = (blk >> 4) & 31, type = blk >> 9;
  int lane = threadIdx.x;
  const float* V = (type == 0 ? Jw : Jr) + ((size_t)bh * Tt + chunk * 128) * 6;
  __shared__ float v[768];
  for (int i = lane; i < 768; i += 64) v[i] = V[i];
  __syncthreads();
  float d = sigm(decay_logits[bh & 15]);
  int ll = lane < 36 ? lane : 35;
  int i6 = ll / 6, j6 = ll % 6;
  float A = 0.f;
  for (int s = 0; s < 128; s++) A = d * A + v[s * 6 + i6] * v[s * 6 + j6];
  if (lane < 36) chunkA[((size_t)(type * 32 + bh) * 16 + chunk) * 36 + lane] = A;
}

__global__ void scanA2_kernel(const float* __restrict__ chunkA,
                              const float* __restrict__ decay_logits,
                              float* __restrict__ Bst) {
  int idx = blockIdx.x * 256 + threadIdx.x;
  if (idx >= 2 * 32 * 36) return;
  int entry = idx % 36, bh = (idx / 36) % 32, type = idx / (36 * 32);
  float d = sigm(decay_logits[bh & 15]);
  float dS = powf(d, 128.f);
  float Bv = 0.f;
  size_t base = (size_t)(type * 32 + bh) * 16;
  for (int c = 0; c < 16; c++) {
    Bst[(base + c) * 36 + entry] = Bv;
    Bv = dS * Bv + d * chunkA[(base + c) * 36 + entry];
  }
}

__global__ __launch_bounds__(128) void scanB_kernel(const float* __restrict__ Jw,
                                                    const float* __restrict__ Jr,
                                                    const float* __restrict__ rd,
                                                    const float* __restrict__ Bst,
                                                    const float* __restrict__ decay_logits,
                                                    float* __restrict__ score_w,
                                                    float* __restrict__ score_r) {
  int blk = blockIdx.x;
  int chunk = blk & 15, bh = (blk >> 4) & 31, type = blk >> 9;
  int tl = threadIdx.x;
  size_t tb = ((size_t)bh * Tt + chunk * 128) * 6;
  const float* U = (type == 0 ? rd : Jw) + tb;
  const float* W = (type == 0 ? Jw : Jr) + tb;
  __shared__ float wv[768];
  __shared__ float Bm[36];
  for (int i = tl; i < 768; i += 128) wv[i] = W[i];
  if (tl < 36) Bm[tl] = Bst[((size_t)(type * 32 + bh) * 16 + chunk) * 36 + tl];
  __syncthreads();
  float d = sigm(decay_logits[bh & 15]);
  float u[6];
#pragma unroll
  for (int i = 0; i < 6; i++) u[i] = U[tl * 6 + i];
  float q = 0.f;
#pragma unroll
  for (int i = 0; i < 6; i++) {
    float bi = 0.f;
#pragma unroll
    for (int j = 0; j < 6; j++) bi += Bm[i * 6 + j] * u[j];
    q += u[i] * bi;
  }
  float acc = 0.f;
  for (int s = 0; s < tl; s++) {
    const float* ws = &wv[s * 6];
    float dot = u[0]*ws[0] + u[1]*ws[1] + u[2]*ws[2] + u[3]*ws[3] + u[4]*ws[4] + u[5]*ws[5];
    acc = d * (acc + dot * dot);
  }
  float score = acc + powf(d, (float)tl) * q;
  float* outp = (type == 0 ? score_w : score_r);
  outp[(size_t)bh * Tt + chunk * 128 + tl] = score;
}

// ---------------- gate + combine (writes swizzled fused for gemm<false>) --------

__global__ __launch_bounds__(256) void combine_kernel(const unsigned short* __restrict__ po,
                                                      const unsigned short* __restrict__ Cq,
                                                      const float* __restrict__ score_w,
                                                      const float* __restrict__ score_r,
                                                      const float* __restrict__ mem_scale,
                                                      const float* __restrict__ rw_mix,
                                                      unsigned short* __restrict__ fused) {
  __shared__ float tmp[16];
  int rowi = blockIdx.x;
  int b = rowi >> 11, t = rowi & 2047;
  float alpha = sigm(rw_mix[0]);
  if (threadIdx.x < 16) {
    int h = threadIdx.x;
    size_t sh = (size_t)(b * 16 + h) * Tt + t;
    float ms = (1.f - alpha) * score_w[sh] + alpha * score_r[sh];
    float gate = sigm(bf2f(Cq[(size_t)rowi * LDC + 3328 + h]));
    tmp[h] = sigm(ms * mem_scale[h]) * gate;
  }
  __syncthreads();
  float g = 0.f;
#pragma unroll
  for (int h = 0; h < 16; h++) g += tmp[h];
  g *= (1.f / 16.f);
  for (int d = threadIdx.x; d < Dd; d += 256) {
    float sv = bf2f(po[((size_t)b * Tt + t) * Dd + d]);
    float mv = bf2f(Cq[(size_t)rowi * LDC + 3392 + d]);
    fused[(size_t)rowi * Dd + swz(rowi, d)] = f2bf(sv + g * mv);
  }
}

// ---------------- launch ----------------

extern "C" void kernel_launch(void* const* d_in, const int* in_sizes, int n_in,
                              void* d_out, int out_size, void* d_ws, size_t ws_size,
                              hipStream_t stream) {
  (void)in_sizes; (void)n_in; (void)out_size; (void)ws_size;
  const float* x         = (const float*)d_in[0];
  const float* qkv_w     = (const float*)d_in[1];
  const float* qkv_b     = (const float*)d_in[2];
  const float* w1w       = (const float*)d_in[3];
  const float* w2w       = (const float*)d_in[4];
  const float* w1r       = (const float*)d_in[5];
  const float* w2r       = (const float*)d_in[6];
  const float* memv_w    = (const float*)d_in[7];
  const float* memv_b    = (const float*)d_in[8];
  const float* memg_w    = (const float*)d_in[9];
  const float* memg_b    = (const float*)d_in[10];
  const float* mem_scale = (const float*)d_in[11];
  const float* rw_mix    = (const float*)d_in[12];
  const float* out_w     = (const float*)d_in[13];
  const float* out_b     = (const float*)d_in[14];
  const float* decay_l   = (const float*)d_in[15];

  char* w = (char*)d_ws;
  unsigned short* xb    = (unsigned short*)(w + 0);          //  8388608
  unsigned short* Kt    = (unsigned short*)(w + 0);          //  overlay (xb dead after gemm)
  unsigned short* WT    = (unsigned short*)(w + 8388608);    //  9175040
  unsigned short* Vt    = (unsigned short*)(w + 8388608);    //  overlay (WT dead after gemm)
  unsigned short* outT  = (unsigned short*)(w + 17563648);   //  2097152
  float*          biasC = (float*)(w + 19660800);            //    17920
  unsigned short* Cbuf  = (unsigned short*)(w + 19678720);   // 36700160
  unsigned short* po    = (unsigned short*)(w + 56378880);   //  8388608
  float*          Jw    = (float*)(w + 73680384);            //  1572864
  float*          Jr    = (float*)(w + 75253248);            //  1572864
  float*          rd    = (float*)(w + 76826112);            //  1572864
  float*          chA   = (float*)(w + 78398976);            //   147456
  float*          Bst   = (float*)(w + 78546432);            //   147456
  float*          sw    = (float*)(w + 78693888);            //   262144
  float*          sr    = (float*)(w + 78956032);            //   262144
  unsigned short* fused = (unsigned short*)(w + 79218176);   //  8388608

  cast_x_kernel<<<2048, 256, 0, stream>>>(x, xb);
  build_wt_kernel<<<dim3(140, 32), 256, 0, stream>>>(qkv_w, w1w, w2w, w1r, w2r,
                                                     memg_w, memv_w, WT);
  transpose_cast_kernel<<<dim3(32, 32), 256, 0, stream>>>(out_w, 1024, outT);
  bias_fill_kernel<<<18, 256, 0, stream>>>(qkv_b, memg_b, memv_b, biasC);

  gemm_kernel<true><<<dim3(35, 32), 256, 0, stream>>>(xb, WT, Cbuf, biasC, 4096, 4480, 1024);

  repack_kernel<<<2048, 256, 0, stream>>>(Cbuf, Kt, Vt);
  attn_kernel<<<dim3(16, 32), 256, 0, stream>>>(Cbuf, Kt, Vt, po);
  lines_kernel<<<256, 256, 0, stream>>>(Cbuf, Jw, Jr, rd);
  scanA_kernel<<<1024, 64, 0, stream>>>(Jw, Jr, decay_l, chA);
  scanA2_kernel<<<9, 256, 0, stream>>>(chA, decay_l, Bst);
  scanB_kernel<<<1024, 128, 0, stream>>>(Jw, Jr, rd, Bst, decay_l, sw, sr);
  combine_kernel<<<4096, 256, 0, stream>>>(po, Cbuf, sw, sr, mem_scale, rw_mix, fused);

  gemm_kernel<false><<<dim3(8, 32), 256, 0, stream>>>(fused, outT, d_out, out_b, 4096, 1024, 1024);
}

// Round 9
// 283.761 us; speedup vs baseline: 1.4863x; 1.0551x over previous
//
#include <hip/hip_runtime.h>

#define Bb 2
#define Tt 2048
#define Dd 1024
#define Hh 16
#define LDC 4480

typedef __attribute__((ext_vector_type(8))) short s16x8;
typedef __attribute__((ext_vector_type(4))) float f32x4;
typedef __attribute__((ext_vector_type(8))) _Float16 f16x8;

__device__ __forceinline__ float bf2f(unsigned short u) {
  unsigned v = ((unsigned)u) << 16;
  union { unsigned u; float f; } c; c.u = v; return c.f;
}
__device__ __forceinline__ unsigned short f2bf(float f) {
  union { float f; unsigned u; } c; c.f = f;
  unsigned u = c.u + 0x7fffu + ((c.u >> 16) & 1u);
  return (unsigned short)(u >> 16);
}
__device__ __forceinline__ float sigm(float x) { return 1.f / (1.f + expf(-x)); }

// XOR chunk swizzle baked into GEMM operand buffers: 16B chunk q of row r
// lives at slot q ^ ((r>>1)&3) within its 32-col group.
__device__ __forceinline__ int swz(int row, int k) {
  return (k & ~31) | (k & 7) | (((((k >> 3) & 3) ^ ((row >> 1) & 3))) << 3);
}

__device__ __forceinline__ void async_copy16(void* lds, const void* g) {
  __builtin_amdgcn_global_load_lds(
      (const __attribute__((address_space(1))) unsigned int*)g,
      (__attribute__((address_space(3))) unsigned int*)lds, 16, 0, 0);
}

// ---------------- fused prep: cast x + build WT + transpose out_w + bias ------

__global__ __launch_bounds__(256) void prep_kernel(const float* __restrict__ x,
                                                   const float* __restrict__ qkv_w,
                                                   const float* __restrict__ w1w,
                                                   const float* __restrict__ w2w,
                                                   const float* __restrict__ w1r,
                                                   const float* __restrict__ w2r,
                                                   const float* __restrict__ memg_w,
                                                   const float* __restrict__ memv_w,
                                                   const float* __restrict__ out_w,
                                                   const float* __restrict__ qkv_b,
                                                   const float* __restrict__ memg_b,
                                                   const float* __restrict__ memv_b,
                                                   unsigned short* __restrict__ xb,
                                                   unsigned short* __restrict__ WT,
                                                   unsigned short* __restrict__ outT,
                                                   float* __restrict__ biasC) {
  __shared__ float tile[32][33];
  int id = blockIdx.x;
  if (id < 2048) {
    // cast x -> bf16 swizzled
    int i = id * 256 + threadIdx.x;
    int row = i >> 7;
    int colbase = (i & 127) * 8;
    const float4* xv = reinterpret_cast<const float4*>(x + (size_t)i * 8);
    float4 a = xv[0], b = xv[1];
    s16x8 out;
    out[0] = (short)f2bf(a.x); out[1] = (short)f2bf(a.y);
    out[2] = (short)f2bf(a.z); out[3] = (short)f2bf(a.w);
    out[4] = (short)f2bf(b.x); out[5] = (short)f2bf(b.y);
    out[6] = (short)f2bf(b.z); out[7] = (short)f2bf(b.w);
    *(s16x8*)&xb[(size_t)row * 1024 + swz(row, colbase)] = out;
  } else if (id < 6528) {
    // build WT (concat transpose cast, swizzled)
    int j = id - 2048;
    int n0 = (j % 140) * 32, k0 = (j / 140) * 32;
    int tx = threadIdx.x & 31, ty = threadIdx.x >> 5;
#pragma unroll
    for (int i = 0; i < 4; i++) {
      int k = k0 + ty + i * 8, n = n0 + tx;
      float v;
      if (n < 3072)       v = qkv_w[(size_t)k * 3072 + n];
      else if (n < 3136)  v = w1w[k * 64 + (n - 3072)];
      else if (n < 3200)  v = w2w[k * 64 + (n - 3136)];
      else if (n < 3264)  v = w1r[k * 64 + (n - 3200)];
      else if (n < 3328)  v = w2r[k * 64 + (n - 3264)];
      else if (n < 3344)  v = memg_w[k * 16 + (n - 3328)];
      else if (n < 3392)  v = 0.f;
      else if (n < 4416)  v = memv_w[(size_t)k * 1024 + (n - 3392)];
      else                v = 0.f;
      tile[ty + i * 8][tx] = v;
    }
    __syncthreads();
#pragma unroll
    for (int i = 0; i < 4; i++) {
      int n = n0 + ty + i * 8, k = k0 + tx;
      WT[(size_t)n * 1024 + swz(n, k)] = f2bf(tile[tx][ty + i * 8]);
    }
  } else if (id < 7552) {
    // transpose out_w -> outT swizzled
    int j = id - 6528;
    int n0 = (j & 31) * 32, k0 = (j >> 5) * 32;
    int tx = threadIdx.x & 31, ty = threadIdx.x >> 5;
#pragma unroll
    for (int i = 0; i < 4; i++) {
      int k = k0 + ty + i * 8, n = n0 + tx;
      tile[ty + i * 8][tx] = out_w[(size_t)k * 1024 + n];
    }
    __syncthreads();
#pragma unroll
    for (int i = 0; i < 4; i++) {
      int n = n0 + ty + i * 8, k = k0 + tx;
      outT[(size_t)n * 1024 + swz(n, k)] = f2bf(tile[tx][ty + i * 8]);
    }
  } else {
    int i = (id - 7552) * 256 + threadIdx.x;
    if (i < LDC) {
      float v = 0.f;
      if (i < 3072) v = qkv_b[i];
      else if (i >= 3328 && i < 3344) v = memg_b[i - 3328];
      else if (i >= 3392 && i < 4416) v = memv_b[i - 3392];
      biasC[i] = v;
    }
  }
}

// ---------------- main bf16 MFMA GEMM: 128x128 tile, BK=64, XCD-partitioned ----

__global__ __launch_bounds__(256) void gemm_kernel(const unsigned short* __restrict__ A,
                                                   const unsigned short* __restrict__ Bt,
                                                   unsigned short* __restrict__ Cout,
                                                   const float* __restrict__ bias) {
  const int K = 1024;
  // XCD-aware 4x2 rectangle partition (assumes id%8 -> XCD round-robin).
  const int x = blockIdx.x & 7, local = blockIdx.x >> 3;
  const int mTile = (x >> 1) * 8 + (local & 7);
  const int nTile = (x & 1) * 18 + (local >> 3);
  if (nTile >= 35) return;  // 32 dummy blocks (grid padded to 1152)
  const int mBase = mTile * 128, nBase = nTile * 128;

  __shared__ unsigned short As0[128 * 32], As1[128 * 32];
  __shared__ unsigned short Bs0[128 * 32], Bs1[128 * 32];
  const int tid = threadIdx.x;
  const int lane = tid & 63, wid = tid >> 6;
  const int quad = lane >> 4, c16 = lane & 15;
  const int wm = wid >> 1, wn = wid & 1;
  const int srow = lane >> 2, scol = (lane & 3) << 3;
  const int slot = (quad ^ ((c16 >> 1) & 3)) * 8;

  f32x4 acc[4][4] = {};
  for (int k0 = 0; k0 < K; k0 += 64) {
    __syncthreads();
#pragma unroll
    for (int j = 0; j < 2; j++) {
      int rr = wid * 32 + j * 16;
      size_t ga = (size_t)(mBase + rr + srow) * K + k0 + scol;
      size_t gb = (size_t)(nBase + rr + srow) * K + k0 + scol;
      async_copy16(&As0[rr * 32], &A[ga]);
      async_copy16(&Bs0[rr * 32], &Bt[gb]);
      async_copy16(&As1[rr * 32], &A[ga + 32]);
      async_copy16(&Bs1[rr * 32], &Bt[gb + 32]);
    }
    __syncthreads();
#pragma unroll
    for (int kk = 0; kk < 2; kk++) {
      const unsigned short* Asp = kk ? As1 : As0;
      const unsigned short* Bsp = kk ? Bs1 : Bs0;
      s16x8 af[4], bf[4];
#pragma unroll
      for (int mt = 0; mt < 4; mt++)
        af[mt] = *(const s16x8*)&Asp[(wm * 64 + mt * 16 + c16) * 32 + slot];
#pragma unroll
      for (int nt = 0; nt < 4; nt++)
        bf[nt] = *(const s16x8*)&Bsp[(wn * 64 + nt * 16 + c16) * 32 + slot];
#pragma unroll
      for (int mt = 0; mt < 4; mt++)
#pragma unroll
        for (int nt = 0; nt < 4; nt++)
          acc[mt][nt] = __builtin_amdgcn_mfma_f32_16x16x32_bf16(af[mt], bf[nt], acc[mt][nt], 0, 0, 0);
    }
  }
#pragma unroll
  for (int mt = 0; mt < 4; mt++)
#pragma unroll
    for (int nt = 0; nt < 4; nt++) {
      int col = nBase + wn * 64 + nt * 16 + c16;
      float bv = bias[col];
#pragma unroll
      for (int r = 0; r < 4; r++) {
        int row = mBase + wm * 64 + mt * 16 + quad * 4 + r;
        Cout[(size_t)row * 4480 + col] = f2bf(acc[mt][nt][r] + bv);
      }
    }
}

// ---------------- out GEMM: 64x128 tile, BK=64, fp32 out (512 blocks) ----------

__global__ __launch_bounds__(256) void gemm_out_kernel(const unsigned short* __restrict__ A,
                                                       const unsigned short* __restrict__ Bt,
                                                       float* __restrict__ Cout,
                                                       const float* __restrict__ bias) {
  const int K = 1024;
  const int mBase = blockIdx.y * 64, nBase = blockIdx.x * 128;
  __shared__ unsigned short As0[64 * 32], As1[64 * 32];
  __shared__ unsigned short Bs0[128 * 32], Bs1[128 * 32];
  const int tid = threadIdx.x;
  const int lane = tid & 63, wid = tid >> 6;
  const int quad = lane >> 4, c16 = lane & 15;
  const int wm = wid >> 1, wn = wid & 1;
  const int srow = lane >> 2, scol = (lane & 3) << 3;
  const int slot = (quad ^ ((c16 >> 1) & 3)) * 8;

  f32x4 acc[2][4] = {};
  for (int k0 = 0; k0 < K; k0 += 64) {
    __syncthreads();
    {
      int rrA = wid * 16;
      size_t ga = (size_t)(mBase + rrA + srow) * K + k0 + scol;
      async_copy16(&As0[rrA * 32], &A[ga]);
      async_copy16(&As1[rrA * 32], &A[ga + 32]);
#pragma unroll
      for (int j = 0; j < 2; j++) {
        int rr = wid * 32 + j * 16;
        size_t gb = (size_t)(nBase + rr + srow) * K + k0 + scol;
        async_copy16(&Bs0[rr * 32], &Bt[gb]);
        async_copy16(&Bs1[rr * 32], &Bt[gb + 32]);
      }
    }
    __syncthreads();
#pragma unroll
    for (int kk = 0; kk < 2; kk++) {
      const unsigned short* Asp = kk ? As1 : As0;
      const unsigned short* Bsp = kk ? Bs1 : Bs0;
      s16x8 af[2], bf[4];
#pragma unroll
      for (int mt = 0; mt < 2; mt++)
        af[mt] = *(const s16x8*)&Asp[(wm * 32 + mt * 16 + c16) * 32 + slot];
#pragma unroll
      for (int nt = 0; nt < 4; nt++)
        bf[nt] = *(const s16x8*)&Bsp[(wn * 64 + nt * 16 + c16) * 32 + slot];
#pragma unroll
      for (int mt = 0; mt < 2; mt++)
#pragma unroll
        for (int nt = 0; nt < 4; nt++)
          acc[mt][nt] = __builtin_amdgcn_mfma_f32_16x16x32_bf16(af[mt], bf[nt], acc[mt][nt], 0, 0, 0);
    }
  }
#pragma unroll
  for (int mt = 0; mt < 2; mt++)
#pragma unroll
    for (int nt = 0; nt < 4; nt++) {
      int col = nBase + wn * 64 + nt * 16 + c16;
      float bv = bias[col];
#pragma unroll
      for (int r = 0; r < 4; r++) {
        int row = mBase + wm * 32 + mt * 16 + quad * 4 + r;
        Cout[(size_t)row * 1024 + col] = acc[mt][nt][r] + bv;
      }
    }
}

// ---------------- Plucker helper ----------------

__device__ __forceinline__ void ext6(const float* p, const float* q, float* L) {
  L[0] = p[0] * q[1] - p[1] * q[0];
  L[1] = p[0] * q[2] - p[2] * q[0];
  L[2] = p[0] * q[3] - p[3] * q[0];
  L[3] = p[1] * q[2] - p[2] * q[1];
  L[4] = p[1] * q[3] - p[3] * q[1];
  L[5] = p[2] * q[3] - p[3] * q[2];
  float n = sqrtf(L[0]*L[0] + L[1]*L[1] + L[2]*L[2] + L[3]*L[3] + L[4]*L[4] + L[5]*L[5]);
  float inv = 1.f / fmaxf(n, 1e-12f);
#pragma unroll
  for (int k = 0; k < 6; k++) L[k] *= inv;
}

// ---------------- post1: repack K/V tiles (blocks<2048) + lines (rest) --------

__global__ __launch_bounds__(256) void post1_kernel(const unsigned short* __restrict__ Cq,
                                                    unsigned short* __restrict__ Kt,
                                                    unsigned short* __restrict__ Vt,
                                                    float* __restrict__ Jw,
                                                    float* __restrict__ Jr,
                                                    float* __restrict__ rd) {
  __shared__ unsigned short vt[32 * 66];
  int id = blockIdx.x;
  int tid = threadIdx.x;
  if (id < 2048) {
    int kb = id & 63, bh = id >> 6;
    int b = bh >> 4, h = bh & 15;
    size_t tbase = ((size_t)bh * 64 + kb) * 2048;
    {
      int key = tid >> 3, p = tid & 7, dg = p ^ (key & 7);
      size_t src = (size_t)(b * Tt + kb * 32 + key) * LDC + 1024 + h * 64 + dg * 8;
      s16x8 kv = *(const s16x8*)&Cq[src];
      *(s16x8*)&Kt[tbase + (size_t)tid * 8] = kv;
    }
    {
      int row = tid >> 3, c = tid & 7;
      size_t src = (size_t)(b * Tt + kb * 32 + row) * LDC + 2048 + h * 64 + c * 8;
      s16x8 vv = *(const s16x8*)&Cq[src];
#pragma unroll
      for (int e = 0; e < 8; e++) {
        union { _Float16 hf; unsigned short s; } cv;
        cv.hf = (_Float16)bf2f((unsigned short)vv[e]);
        vt[row * 66 + c * 8 + e] = cv.s;
      }
    }
    __syncthreads();
    {
      int d = tid >> 2, p = tid & 3, cq = p ^ ((d >> 2) & 3);
      s16x8 out;
#pragma unroll
      for (int e = 0; e < 8; e++) {
        int key = ((e >> 2) & 1) * 16 + cq * 4 + (e & 3);
        out[e] = (short)vt[key * 66 + d];
      }
      *(s16x8*)&Vt[tbase + (size_t)tid * 8] = out;
    }
  } else {
    int idx = (id - 2048) * 256 + tid;
    int h = idx & 15, t = (idx >> 4) & 2047, b = idx >> 15;
    size_t row = (size_t)(b * Tt + t) * LDC;
    float w1[4], w2[4], r1[4], r2[4];
#pragma unroll
    for (int k = 0; k < 4; k++) {
      w1[k] = (t > 0) ? bf2f(Cq[row - LDC + 3072 + h * 4 + k]) : 0.f;
      w2[k] = bf2f(Cq[row + 3136 + h * 4 + k]);
      r1[k] = bf2f(Cq[row + 3200 + h * 4 + k]);
      r2[k] = bf2f(Cq[row + 3264 + h * 4 + k]);
    }
    float Lw[6], Lr[6];
    ext6(w1, w2, Lw);
    ext6(r1, r2, Lr);
    size_t ob = ((size_t)(b * Hh + h) * Tt + t) * 6;
    Jw[ob + 0] = Lw[5]; Jw[ob + 1] = -Lw[4]; Jw[ob + 2] = Lw[3];
    Jw[ob + 3] = Lw[2]; Jw[ob + 4] = -Lw[1]; Jw[ob + 5] = Lw[0];
    Jr[ob + 0] = Lr[5]; Jr[ob + 1] = -Lr[4]; Jr[ob + 2] = Lr[3];
    Jr[ob + 3] = Lr[2]; Jr[ob + 4] = -Lr[1]; Jr[ob + 5] = Lr[0];
#pragma unroll
    for (int k = 0; k < 6; k++) rd[ob + k] = Lr[k];
  }
}

// ---------------- block-cooperative MFMA flash attention ----------------

__device__ __forceinline__ void do_tile(int ks, int q0, int quad, int c16,
                                        const s16x8& qf0, const s16x8& qf1,
                                        const s16x8 kf[2][2], const f16x8 vb[4],
                                        float& l_i, f32x4 o[4]) {
  f32x4 st0 = {}, st1 = {};
  st0 = __builtin_amdgcn_mfma_f32_16x16x32_bf16(kf[0][0], qf0, st0, 0, 0, 0);
  st0 = __builtin_amdgcn_mfma_f32_16x16x32_bf16(kf[0][1], qf1, st0, 0, 0, 0);
  st1 = __builtin_amdgcn_mfma_f32_16x16x32_bf16(kf[1][0], qf0, st1, 0, 0, 0);
  st1 = __builtin_amdgcn_mfma_f32_16x16x32_bf16(kf[1][1], qf1, st1, 0, 0, 0);
  bool need_mask = (ks + 31 > q0);
  f16x8 pa;
  float lp = 0.f;
#pragma unroll
  for (int r = 0; r < 4; r++) {
    float v0 = st0[r] * 0.125f;
    float v1 = st1[r] * 0.125f;
    if (need_mask) {
      v0 = (ks + quad * 4 + r      <= q0 + c16) ? v0 : -1e30f;
      v1 = (ks + 16 + quad * 4 + r <= q0 + c16) ? v1 : -1e30f;
    }
    float p0 = __expf(v0);
    float p1 = __expf(v1);
    lp += p0 + p1;
    pa[r]     = (_Float16)p0;
    pa[4 + r] = (_Float16)p1;
  }
  l_i += lp;
#pragma unroll
  for (int nt = 0; nt < 4; nt++)
    o[nt] = __builtin_amdgcn_mfma_f32_16x16x32_f16(pa, vb[nt], o[nt], 0, 0, 0);
}

__global__ __launch_bounds__(256) void attn_kernel(const unsigned short* __restrict__ Cq,
                                                   const unsigned short* __restrict__ Kt,
                                                   const unsigned short* __restrict__ Vt,
                                                   unsigned short* __restrict__ po) {
  __shared__ unsigned short Kl[2048];
  __shared__ unsigned short Vl[2048];
  const int g0 = blockIdx.x, bh = blockIdx.y;
  const int g = ((bh >> 4) & 1) ? (15 - g0) : g0;
  const int b = bh >> 4, h = bh & 15;
  const int w = threadIdx.x >> 6, lane = threadIdx.x & 63;
  const int quad = lane >> 4, c16 = lane & 15;
  const int pi = g * 4 + w;
  const int qA = pi * 16, qB = 2032 - pi * 16;
  const int nkA = qA + 16, nkB = 2048 - pi * 16;
  const int bound = 2048 - 64 * g;
  const unsigned short* Ktb = Kt + (size_t)bh * 64 * 2048;
  const unsigned short* Vtb = Vt + (size_t)bh * 64 * 2048;
  const int ci = threadIdx.x;

  size_t rowA = (size_t)(b * Tt + qA + c16) * LDC + h * 64;
  size_t rowB = (size_t)(b * Tt + qB + c16) * LDC + h * 64;
  s16x8 qA0 = *(const s16x8*)&Cq[rowA + quad * 8];
  s16x8 qA1 = *(const s16x8*)&Cq[rowA + 32 + quad * 8];
  s16x8 qB0 = *(const s16x8*)&Cq[rowB + quad * 8];
  s16x8 qB1 = *(const s16x8*)&Cq[rowB + 32 + quad * 8];

  float lA = 0.f, lB = 0.f;
  f32x4 oA[4] = {}, oB[4] = {};

  {
    s16x8 k0 = *(const s16x8*)&Ktb[(size_t)ci * 8];
    s16x8 v0 = *(const s16x8*)&Vtb[(size_t)ci * 8];
    *(s16x8*)&Kl[ci * 8] = k0;
    *(s16x8*)&Vl[ci * 8] = v0;
  }
  __syncthreads();

  for (int ks = 0; ks < bound; ks += 32) {
    bool more = (ks + 32) < bound;
    s16x8 kreg, vreg;
    if (more) {
      size_t nb = ((size_t)(ks >> 5) + 1) * 2048 + (size_t)ci * 8;
      kreg = *(const s16x8*)&Ktb[nb];
      vreg = *(const s16x8*)&Vtb[nb];
    }
    if (ks < nkB) {
      s16x8 kf[2][2];
#pragma unroll
      for (int gg = 0; gg < 2; gg++)
#pragma unroll
        for (int half = 0; half < 2; half++) {
          int key = gg * 16 + c16;
          int p = (half * 4 + quad) ^ (c16 & 7);
          kf[gg][half] = *(const s16x8*)&Kl[(key * 8 + p) * 8];
        }
      f16x8 vb[4];
#pragma unroll
      for (int nt = 0; nt < 4; nt++) {
        int d = nt * 16 + c16;
        int p = quad ^ ((d >> 2) & 3);
        vb[nt] = *(const f16x8*)&Vl[(d * 4 + p) * 8];
      }
      do_tile(ks, qB, quad, c16, qB0, qB1, kf, vb, lB, oB);
      if (ks < nkA)
        do_tile(ks, qA, quad, c16, qA0, qA1, kf, vb, lA, oA);
    }
    __syncthreads();
    if (more) {
      *(s16x8*)&Kl[ci * 8] = kreg;
      *(s16x8*)&Vl[ci * 8] = vreg;
      __syncthreads();
    }
  }

  lB += __shfl_xor(lB, 16, 64); lB += __shfl_xor(lB, 32, 64);
  lA += __shfl_xor(lA, 16, 64); lA += __shfl_xor(lA, 32, 64);
  float invB = 1.f / lB, invA = 1.f / lA;
#pragma unroll
  for (int r = 0; r < 4; r++) {
    float ivB = __shfl(invB, quad * 4 + r, 64);
    float ivA = __shfl(invA, quad * 4 + r, 64);
    size_t baseB = (size_t)(b * Tt + qB + quad * 4 + r) * Dd + h * 64;
    size_t baseA = (size_t)(b * Tt + qA + quad * 4 + r) * Dd + h * 64;
#pragma unroll
    for (int nt = 0; nt < 4; nt++) {
      po[baseB + nt * 16 + c16] = f2bf(oB[nt][r] * ivB);
      po[baseA + nt * 16 + c16] = f2bf(oA[nt][r] * ivA);
    }
  }
}

// ---------------- chunked decay scan ----------------

__global__ __launch_bounds__(64) void scanA_kernel(const float* __restrict__ Jw,
                                                   const float* __restrict__ Jr,
                                                   const float* __restrict__ decay_logits,
                                                   float* __restrict__ chunkA) {
  int blk = blockIdx.x;
  int chunk = blk & 15, bh = (blk >> 4) & 31, type = blk >> 9;
  int lane = threadIdx.x;
  const float* V = (type == 0 ? Jw : Jr) + ((size_t)bh * Tt + chunk * 128) * 6;
  __shared__ float v[768];
  for (int i = lane; i < 768; i += 64) v[i] = V[i];
  __syncthreads();
  float d = sigm(decay_logits[bh & 15]);
  int ll = lane < 36 ? lane : 35;
  int i6 = ll / 6, j6 = ll % 6;
  float A = 0.f;
  for (int s = 0; s < 128; s++) A = d * A + v[s * 6 + i6] * v[s * 6 + j6];
  if (lane < 36) chunkA[((size_t)(type * 32 + bh) * 16 + chunk) * 36 + lane] = A;
}

// scanB with inline cross-chunk prefix:
// B_chunk = sum_{c<chunk} dS^(chunk-1-c) * d * chunkA[c]
// score(t) = d^tl * (u^T B u) + sum_{s<tl} d^(tl-s) (u.w_s)^2

__global__ __launch_bounds__(128) void scanB_kernel(const float* __restrict__ Jw,
                                                    const float* __restrict__ Jr,
                                                    const float* __restrict__ rd,
                                                    const float* __restrict__ chunkA,
                                                    const float* __restrict__ decay_logits,
                                                    float* __restrict__ score_w,
                                                    float* __restrict__ score_r) {
  int blk = blockIdx.x;
  int chunk = blk & 15, bh = (blk >> 4) & 31, type = blk >> 9;
  int tl = threadIdx.x;
  size_t tb = ((size_t)bh * Tt + chunk * 128) * 6;
  const float* U = (type == 0 ? rd : Jw) + tb;
  const float* W = (type == 0 ? Jw : Jr) + tb;
  __shared__ float wv[768];
  __shared__ float Bm[36];
  for (int i = tl; i < 768; i += 128) wv[i] = W[i];
  float d = sigm(decay_logits[bh & 15]);
  if (tl < 36) {
    float dS = powf(d, 128.f);
    float Bv = 0.f;
    size_t base = (size_t)(type * 32 + bh) * 16;
    for (int c = 0; c < chunk; c++)
      Bv = dS * Bv + d * chunkA[(base + c) * 36 + tl];
    Bm[tl] = Bv;
  }
  __syncthreads();
  float u[6];
#pragma unroll
  for (int i = 0; i < 6; i++) u[i] = U[tl * 6 + i];
  float q = 0.f;
#pragma unroll
  for (int i = 0; i < 6; i++) {
    float bi = 0.f;
#pragma unroll
    for (int j = 0; j < 6; j++) bi += Bm[i * 6 + j] * u[j];
    q += u[i] * bi;
  }
  float acc = 0.f;
  for (int s = 0; s < tl; s++) {
    const float* ws = &wv[s * 6];
    float dot = u[0]*ws[0] + u[1]*ws[1] + u[2]*ws[2] + u[3]*ws[3] + u[4]*ws[4] + u[5]*ws[5];
    acc = d * (acc + dot * dot);
  }
  float score = acc + powf(d, (float)tl) * q;
  float* outp = (type == 0 ? score_w : score_r);
  outp[(size_t)bh * Tt + chunk * 128 + tl] = score;
}

// ---------------- gate + combine (writes swizzled fused) ----------------

__global__ __launch_bounds__(256) void combine_kernel(const unsigned short* __restrict__ po,
                                                      const unsigned short* __restrict__ Cq,
                                                      const float* __restrict__ score_w,
                                                      const float* __restrict__ score_r,
                                                      const float* __restrict__ mem_scale,
                                                      const float* __restrict__ rw_mix,
                                                      unsigned short* __restrict__ fused) {
  __shared__ float tmp[16];
  int rowi = blockIdx.x;
  int b = rowi >> 11, t = rowi & 2047;
  float alpha = sigm(rw_mix[0]);
  if (threadIdx.x < 16) {
    int h = threadIdx.x;
    size_t sh = (size_t)(b * 16 + h) * Tt + t;
    float ms = (1.f - alpha) * score_w[sh] + alpha * score_r[sh];
    float gate = sigm(bf2f(Cq[(size_t)rowi * LDC + 3328 + h]));
    tmp[h] = sigm(ms * mem_scale[h]) * gate;
  }
  __syncthreads();
  float g = 0.f;
#pragma unroll
  for (int h = 0; h < 16; h++) g += tmp[h];
  g *= (1.f / 16.f);
  for (int d = threadIdx.x; d < Dd; d += 256) {
    float sv = bf2f(po[((size_t)b * Tt + t) * Dd + d]);
    float mv = bf2f(Cq[(size_t)rowi * LDC + 3392 + d]);
    fused[(size_t)rowi * Dd + swz(rowi, d)] = f2bf(sv + g * mv);
  }
}

// ---------------- launch ----------------

extern "C" void kernel_launch(void* const* d_in, const int* in_sizes, int n_in,
                              void* d_out, int out_size, void* d_ws, size_t ws_size,
                              hipStream_t stream) {
  (void)in_sizes; (void)n_in; (void)out_size; (void)ws_size;
  const float* x         = (const float*)d_in[0];
  const float* qkv_w     = (const float*)d_in[1];
  const float* qkv_b     = (const float*)d_in[2];
  const float* w1w       = (const float*)d_in[3];
  const float* w2w       = (const float*)d_in[4];
  const float* w1r       = (const float*)d_in[5];
  const float* w2r       = (const float*)d_in[6];
  const float* memv_w    = (const float*)d_in[7];
  const float* memv_b    = (const float*)d_in[8];
  const float* memg_w    = (const float*)d_in[9];
  const float* memg_b    = (const float*)d_in[10];
  const float* mem_scale = (const float*)d_in[11];
  const float* rw_mix    = (const float*)d_in[12];
  const float* out_w     = (const float*)d_in[13];
  const float* out_b     = (const float*)d_in[14];
  const float* decay_l   = (const float*)d_in[15];

  char* w = (char*)d_ws;
  unsigned short* xb    = (unsigned short*)(w + 0);          //  8388608
  unsigned short* Kt    = (unsigned short*)(w + 0);          //  overlay (xb dead after gemm)
  unsigned short* WT    = (unsigned short*)(w + 8388608);    //  9175040
  unsigned short* Vt    = (unsigned short*)(w + 8388608);    //  overlay (WT dead after gemm)
  unsigned short* outT  = (unsigned short*)(w + 17563648);   //  2097152
  float*          biasC = (float*)(w + 19660800);            //    17920
  unsigned short* Cbuf  = (unsigned short*)(w + 19678720);   // 36700160
  unsigned short* po    = (unsigned short*)(w + 56378880);   //  8388608
  float*          Jw    = (float*)(w + 73680384);            //  1572864
  float*          Jr    = (float*)(w + 75253248);            //  1572864
  float*          rd    = (float*)(w + 76826112);            //  1572864
  float*          chA   = (float*)(w + 78398976);            //   147456
  float*          sw    = (float*)(w + 78693888);            //   262144
  float*          sr    = (float*)(w + 78956032);            //   262144
  unsigned short* fused = (unsigned short*)(w + 79218176);   //  8388608

  prep_kernel<<<7570, 256, 0, stream>>>(x, qkv_w, w1w, w2w, w1r, w2r, memg_w, memv_w,
                                        out_w, qkv_b, memg_b, memv_b,
                                        xb, WT, outT, biasC);

  gemm_kernel<<<1152, 256, 0, stream>>>(xb, WT, Cbuf, biasC);

  post1_kernel<<<2304, 256, 0, stream>>>(Cbuf, Kt, Vt, Jw, Jr, rd);
  attn_kernel<<<dim3(16, 32), 256, 0, stream>>>(Cbuf, Kt, Vt, po);
  scanA_kernel<<<1024, 64, 0, stream>>>(Jw, Jr, decay_l, chA);
  scanB_kernel<<<1024, 128, 0, stream>>>(Jw, Jr, rd, chA, decay_l, sw, sr);
  combine_kernel<<<4096, 256, 0, stream>>>(po, Cbuf, sw, sr, mem_scale, rw_mix, fused);

  gemm_out_kernel<<<dim3(8, 64), 256, 0, stream>>>(fused, outT, (float*)d_out, out_b);
}

// Round 11
// 278.321 us; speedup vs baseline: 1.5154x; 1.0195x over previous
//
#include <hip/hip_runtime.h>

#define Bb 2
#define Tt 2048
#define Dd 1024
#define Hh 16
#define LDC 4480

typedef __attribute__((ext_vector_type(8))) short s16x8;
typedef __attribute__((ext_vector_type(4))) float f32x4;
typedef __attribute__((ext_vector_type(8))) _Float16 f16x8;

__device__ __forceinline__ float bf2f(unsigned short u) {
  unsigned v = ((unsigned)u) << 16;
  union { unsigned u; float f; } c; c.u = v; return c.f;
}
__device__ __forceinline__ unsigned short f2bf(float f) {
  union { float f; unsigned u; } c; c.f = f;
  unsigned u = c.u + 0x7fffu + ((c.u >> 16) & 1u);
  return (unsigned short)(u >> 16);
}
__device__ __forceinline__ float sigm(float x) { return 1.f / (1.f + expf(-x)); }

// Fragment-major operand layout: frag(t16, kt) holds 64 lanes x 16 B where
// lane = (row&15) + quad*16, bytes = elems [kt*32 + quad*8 .. +8) of row.
// One wave loads a fragment with a single coalesced global_load_dwordx4.

// ---------------- fused prep: cast x + build WT + transpose out_w + bias ------

__global__ __launch_bounds__(256) void prep_kernel(const float* __restrict__ x,
                                                   const float* __restrict__ qkv_w,
                                                   const float* __restrict__ w1w,
                                                   const float* __restrict__ w2w,
                                                   const float* __restrict__ w1r,
                                                   const float* __restrict__ w2r,
                                                   const float* __restrict__ memg_w,
                                                   const float* __restrict__ memv_w,
                                                   const float* __restrict__ out_w,
                                                   const float* __restrict__ qkv_b,
                                                   const float* __restrict__ memg_b,
                                                   const float* __restrict__ memv_b,
                                                   unsigned short* __restrict__ xb,
                                                   unsigned short* __restrict__ WT,
                                                   unsigned short* __restrict__ outT,
                                                   float* __restrict__ biasC) {
  __shared__ float tile[32][33];
  int id = blockIdx.x;
  if (id < 2048) {
    // cast x -> A-fragment-major bf16
    int i = id * 256 + threadIdx.x;     // 16B chunk index
    int row = i >> 7;
    int k8 = i & 127;                    // 8-elem group
    const float4* xv = reinterpret_cast<const float4*>(x + (size_t)i * 8);
    float4 a = xv[0], b = xv[1];
    s16x8 out;
    out[0] = (short)f2bf(a.x); out[1] = (short)f2bf(a.y);
    out[2] = (short)f2bf(a.z); out[3] = (short)f2bf(a.w);
    out[4] = (short)f2bf(b.x); out[5] = (short)f2bf(b.y);
    out[6] = (short)f2bf(b.z); out[7] = (short)f2bf(b.w);
    int mt = row >> 4, kt = k8 >> 2, quad = k8 & 3;
    int lane = (row & 15) + quad * 16;
    *(s16x8*)&xb[(((size_t)mt * 32 + kt) * 64 + lane) * 8] = out;
  } else if (id < 6528) {
    // build WT (concat) -> B-fragment-major
    int j = id - 2048;
    int n0 = (j % 140) * 32, kt = j / 140, k0 = kt * 32;
    int tx = threadIdx.x & 31, ty = threadIdx.x >> 5;
#pragma unroll
    for (int i = 0; i < 4; i++) {
      int k = k0 + ty + i * 8, n = n0 + tx;
      float v;
      if (n < 3072)       v = qkv_w[(size_t)k * 3072 + n];
      else if (n < 3136)  v = w1w[k * 64 + (n - 3072)];
      else if (n < 3200)  v = w2w[k * 64 + (n - 3136)];
      else if (n < 3264)  v = w1r[k * 64 + (n - 3200)];
      else if (n < 3328)  v = w2r[k * 64 + (n - 3264)];
      else if (n < 3344)  v = memg_w[k * 16 + (n - 3328)];
      else if (n < 3392)  v = 0.f;
      else if (n < 4416)  v = memv_w[(size_t)k * 1024 + (n - 3392)];
      else                v = 0.f;
      tile[ty + i * 8][tx] = v;
    }
    __syncthreads();
    if (threadIdx.x < 128) {
      int nl = threadIdx.x & 31, quad = threadIdx.x >> 5;
      s16x8 out;
#pragma unroll
      for (int e = 0; e < 8; e++) out[e] = (short)f2bf(tile[quad * 8 + e][nl]);
      int nt = (n0 >> 4) + (nl >> 4);
      int lane = (nl & 15) + quad * 16;
      *(s16x8*)&WT[(((size_t)nt * 32 + kt) * 64 + lane) * 8] = out;
    }
  } else if (id < 7552) {
    // transpose out_w -> B-fragment-major outT
    int j = id - 6528;
    int n0 = (j & 31) * 32, kt = j >> 5, k0 = kt * 32;
    int tx = threadIdx.x & 31, ty = threadIdx.x >> 5;
#pragma unroll
    for (int i = 0; i < 4; i++) {
      int k = k0 + ty + i * 8, n = n0 + tx;
      tile[ty + i * 8][tx] = out_w[(size_t)k * 1024 + n];
    }
    __syncthreads();
    if (threadIdx.x < 128) {
      int nl = threadIdx.x & 31, quad = threadIdx.x >> 5;
      s16x8 out;
#pragma unroll
      for (int e = 0; e < 8; e++) out[e] = (short)f2bf(tile[quad * 8 + e][nl]);
      int nt = (n0 >> 4) + (nl >> 4);
      int lane = (nl & 15) + quad * 16;
      *(s16x8*)&outT[(((size_t)nt * 32 + kt) * 64 + lane) * 8] = out;
    }
  } else {
    int i = (id - 7552) * 256 + threadIdx.x;
    if (i < LDC) {
      float v = 0.f;
      if (i < 3072) v = qkv_b[i];
      else if (i >= 3328 && i < 3344) v = memg_b[i - 3328];
      else if (i >= 3392 && i < 4416) v = memv_b[i - 3392];
      biasC[i] = v;
    }
  }
}

// ---------------- LDS-free fragment-direct MFMA GEMM ----------------
// MODE 0: 4096x4480 bf16-out (XCD-partitioned grid, 1152 blocks, 32 dummy)
// MODE 1: 4096x1024 fp32-out (256 blocks)

template <int MODE>
__global__ __launch_bounds__(256) void gemm_frag_kernel(const unsigned short* __restrict__ Af,
                                                        const unsigned short* __restrict__ Bf,
                                                        void* __restrict__ Cout,
                                                        const float* __restrict__ bias) {
  int mTile, nTile;
  if (MODE == 0) {
    const int xx = blockIdx.x & 7, local = blockIdx.x >> 3;
    mTile = (xx >> 1) * 8 + (local & 7);
    nTile = (xx & 1) * 18 + (local >> 3);
    if (nTile >= 35) return;
  } else {
    mTile = blockIdx.x >> 3;
    nTile = blockIdx.x & 7;
  }
  const int lane = threadIdx.x & 63, wid = threadIdx.x >> 6;
  const int quad = lane >> 4, c16 = lane & 15;
  const int wm = wid >> 1, wn = wid & 1;
  const int mt0 = mTile * 8 + wm * 4;   // global 16-row tile index
  const int nt0 = nTile * 8 + wn * 4;
  const unsigned short* Apt = Af + ((size_t)mt0 * 32 * 64 + lane) * 8;
  const unsigned short* Bpt = Bf + ((size_t)nt0 * 32 * 64 + lane) * 8;
  // offsets: +mt*16384 shorts (32 kt * 512), +kt*512 shorts

  f32x4 acc[4][4] = {};
  s16x8 af[2][4], bf[2][4];
#pragma unroll
  for (int i = 0; i < 4; i++) {
    af[0][i] = *(const s16x8*)(Apt + (size_t)i * 16384);
    bf[0][i] = *(const s16x8*)(Bpt + (size_t)i * 16384);
  }
#pragma unroll
  for (int kt = 0; kt < 32; kt++) {
    const int cur = kt & 1, nxt = cur ^ 1;
    if (kt + 1 < 32) {
      const unsigned short* An = Apt + (size_t)(kt + 1) * 512;
      const unsigned short* Bn = Bpt + (size_t)(kt + 1) * 512;
#pragma unroll
      for (int i = 0; i < 4; i++) {
        af[nxt][i] = *(const s16x8*)(An + (size_t)i * 16384);
        bf[nxt][i] = *(const s16x8*)(Bn + (size_t)i * 16384);
      }
    }
#pragma unroll
    for (int mt = 0; mt < 4; mt++)
#pragma unroll
      for (int nt = 0; nt < 4; nt++)
        acc[mt][nt] = __builtin_amdgcn_mfma_f32_16x16x32_bf16(af[cur][mt], bf[cur][nt],
                                                              acc[mt][nt], 0, 0, 0);
  }

#pragma unroll
  for (int mt = 0; mt < 4; mt++)
#pragma unroll
    for (int nt = 0; nt < 4; nt++) {
      int col = (nt0 + nt) * 16 + c16;
      float bv = bias[col];
#pragma unroll
      for (int r = 0; r < 4; r++) {
        int row = (mt0 + mt) * 16 + quad * 4 + r;
        if (MODE == 0)
          ((unsigned short*)Cout)[(size_t)row * 4480 + col] = f2bf(acc[mt][nt][r] + bv);
        else
          ((float*)Cout)[(size_t)row * 1024 + col] = acc[mt][nt][r] + bv;
      }
    }
}

// ---------------- Plucker helper ----------------

__device__ __forceinline__ void ext6(const float* p, const float* q, float* L) {
  L[0] = p[0] * q[1] - p[1] * q[0];
  L[1] = p[0] * q[2] - p[2] * q[0];
  L[2] = p[0] * q[3] - p[3] * q[0];
  L[3] = p[1] * q[2] - p[2] * q[1];
  L[4] = p[1] * q[3] - p[3] * q[1];
  L[5] = p[2] * q[3] - p[3] * q[2];
  float n = sqrtf(L[0]*L[0] + L[1]*L[1] + L[2]*L[2] + L[3]*L[3] + L[4]*L[4] + L[5]*L[5]);
  float inv = 1.f / fmaxf(n, 1e-12f);
#pragma unroll
  for (int k = 0; k < 6; k++) L[k] *= inv;
}

// ---------------- post1: repack K/V tiles (blocks<2048) + lines (rest) --------

__global__ __launch_bounds__(256) void post1_kernel(const unsigned short* __restrict__ Cq,
                                                    unsigned short* __restrict__ Kt,
                                                    unsigned short* __restrict__ Vt,
                                                    float* __restrict__ Jw,
                                                    float* __restrict__ Jr,
                                                    float* __restrict__ rd) {
  __shared__ unsigned short vt[32 * 66];
  int id = blockIdx.x;
  int tid = threadIdx.x;
  if (id < 2048) {
    int kb = id & 63, bh = id >> 6;
    int b = bh >> 4, h = bh & 15;
    size_t tbase = ((size_t)bh * 64 + kb) * 2048;
    {
      int key = tid >> 3, p = tid & 7, dg = p ^ (key & 7);
      size_t src = (size_t)(b * Tt + kb * 32 + key) * LDC + 1024 + h * 64 + dg * 8;
      s16x8 kv = *(const s16x8*)&Cq[src];
      *(s16x8*)&Kt[tbase + (size_t)tid * 8] = kv;
    }
    {
      int row = tid >> 3, c = tid & 7;
      size_t src = (size_t)(b * Tt + kb * 32 + row) * LDC + 2048 + h * 64 + c * 8;
      s16x8 vv = *(const s16x8*)&Cq[src];
#pragma unroll
      for (int e = 0; e < 8; e++) {
        union { _Float16 hf; unsigned short s; } cv;
        cv.hf = (_Float16)bf2f((unsigned short)vv[e]);
        vt[row * 66 + c * 8 + e] = cv.s;
      }
    }
    __syncthreads();
    {
      int d = tid >> 2, p = tid & 3, cq = p ^ ((d >> 2) & 3);
      s16x8 out;
#pragma unroll
      for (int e = 0; e < 8; e++) {
        int key = ((e >> 2) & 1) * 16 + cq * 4 + (e & 3);
        out[e] = (short)vt[key * 66 + d];
      }
      *(s16x8*)&Vt[tbase + (size_t)tid * 8] = out;
    }
  } else {
    int idx = (id - 2048) * 256 + tid;
    int h = idx & 15, t = (idx >> 4) & 2047, b = idx >> 15;
    size_t row = (size_t)(b * Tt + t) * LDC;
    float w1[4], w2[4], r1[4], r2[4];
#pragma unroll
    for (int k = 0; k < 4; k++) {
      w1[k] = (t > 0) ? bf2f(Cq[row - LDC + 3072 + h * 4 + k]) : 0.f;
      w2[k] = bf2f(Cq[row + 3136 + h * 4 + k]);
      r1[k] = bf2f(Cq[row + 3200 + h * 4 + k]);
      r2[k] = bf2f(Cq[row + 3264 + h * 4 + k]);
    }
    float Lw[6], Lr[6];
    ext6(w1, w2, Lw);
    ext6(r1, r2, Lr);
    size_t ob = ((size_t)(b * Hh + h) * Tt + t) * 6;
    Jw[ob + 0] = Lw[5]; Jw[ob + 1] = -Lw[4]; Jw[ob + 2] = Lw[3];
    Jw[ob + 3] = Lw[2]; Jw[ob + 4] = -Lw[1]; Jw[ob + 5] = Lw[0];
    Jr[ob + 0] = Lr[5]; Jr[ob + 1] = -Lr[4]; Jr[ob + 2] = Lr[3];
    Jr[ob + 3] = Lr[2]; Jr[ob + 4] = -Lr[1]; Jr[ob + 5] = Lr[0];
#pragma unroll
    for (int k = 0; k < 6; k++) rd[ob + k] = Lr[k];
  }
}

// ---------------- block-cooperative MFMA flash attention ----------------

__device__ __forceinline__ void do_tile(int ks, int q0, int quad, int c16,
                                        const s16x8& qf0, const s16x8& qf1,
                                        const s16x8 kf[2][2], const f16x8 vb[4],
                                        float& l_i, f32x4 o[4]) {
  f32x4 st0 = {}, st1 = {};
  st0 = __builtin_amdgcn_mfma_f32_16x16x32_bf16(kf[0][0], qf0, st0, 0, 0, 0);
  st0 = __builtin_amdgcn_mfma_f32_16x16x32_bf16(kf[0][1], qf1, st0, 0, 0, 0);
  st1 = __builtin_amdgcn_mfma_f32_16x16x32_bf16(kf[1][0], qf0, st1, 0, 0, 0);
  st1 = __builtin_amdgcn_mfma_f32_16x16x32_bf16(kf[1][1], qf1, st1, 0, 0, 0);
  bool need_mask = (ks + 31 > q0);
  f16x8 pa;
  float lp = 0.f;
#pragma unroll
  for (int r = 0; r < 4; r++) {
    float v0 = st0[r] * 0.125f;
    float v1 = st1[r] * 0.125f;
    if (need_mask) {
      v0 = (ks + quad * 4 + r      <= q0 + c16) ? v0 : -1e30f;
      v1 = (ks + 16 + quad * 4 + r <= q0 + c16) ? v1 : -1e30f;
    }
    float p0 = __expf(v0);
    float p1 = __expf(v1);
    lp += p0 + p1;
    pa[r]     = (_Float16)p0;
    pa[4 + r] = (_Float16)p1;
  }
  l_i += lp;
#pragma unroll
  for (int nt = 0; nt < 4; nt++)
    o[nt] = __builtin_amdgcn_mfma_f32_16x16x32_f16(pa, vb[nt], o[nt], 0, 0, 0);
}

__global__ __launch_bounds__(256) void attn_kernel(const unsigned short* __restrict__ Cq,
                                                   const unsigned short* __restrict__ Kt,
                                                   const unsigned short* __restrict__ Vt,
                                                   unsigned short* __restrict__ po) {
  __shared__ unsigned short Kl[2048];
  __shared__ unsigned short Vl[2048];
  const int g0 = blockIdx.x, bh = blockIdx.y;
  const int g = ((bh >> 4) & 1) ? (15 - g0) : g0;
  const int b = bh >> 4, h = bh & 15;
  const int w = threadIdx.x >> 6, lane = threadIdx.x & 63;
  const int quad = lane >> 4, c16 = lane & 15;
  const int pi = g * 4 + w;
  const int qA = pi * 16, qB = 2032 - pi * 16;
  const int nkA = qA + 16, nkB = 2048 - pi * 16;
  const int bound = 2048 - 64 * g;
  const unsigned short* Ktb = Kt + (size_t)bh * 64 * 2048;
  const unsigned short* Vtb = Vt + (size_t)bh * 64 * 2048;
  const int ci = threadIdx.x;

  size_t rowA = (size_t)(b * Tt + qA + c16) * LDC + h * 64;
  size_t rowB = (size_t)(b * Tt + qB + c16) * LDC + h * 64;
  s16x8 qA0 = *(const s16x8*)&Cq[rowA + quad * 8];
  s16x8 qA1 = *(const s16x8*)&Cq[rowA + 32 + quad * 8];
  s16x8 qB0 = *(const s16x8*)&Cq[rowB + quad * 8];
  s16x8 qB1 = *(const s16x8*)&Cq[rowB + 32 + quad * 8];

  float lA = 0.f, lB = 0.f;
  f32x4 oA[4] = {}, oB[4] = {};

  {
    s16x8 k0 = *(const s16x8*)&Ktb[(size_t)ci * 8];
    s16x8 v0 = *(const s16x8*)&Vtb[(size_t)ci * 8];
    *(s16x8*)&Kl[ci * 8] = k0;
    *(s16x8*)&Vl[ci * 8] = v0;
  }
  __syncthreads();

  for (int ks = 0; ks < bound; ks += 32) {
    bool more = (ks + 32) < bound;
    s16x8 kreg, vreg;
    if (more) {
      size_t nb = ((size_t)(ks >> 5) + 1) * 2048 + (size_t)ci * 8;
      kreg = *(const s16x8*)&Ktb[nb];
      vreg = *(const s16x8*)&Vtb[nb];
    }
    if (ks < nkB) {
      s16x8 kf[2][2];
#pragma unroll
      for (int gg = 0; gg < 2; gg++)
#pragma unroll
        for (int half = 0; half < 2; half++) {
          int key = gg * 16 + c16;
          int p = (half * 4 + quad) ^ (c16 & 7);
          kf[gg][half] = *(const s16x8*)&Kl[(key * 8 + p) * 8];
        }
      f16x8 vb[4];
#pragma unroll
      for (int nt = 0; nt < 4; nt++) {
        int d = nt * 16 + c16;
        int p = quad ^ ((d >> 2) & 3);
        vb[nt] = *(const f16x8*)&Vl[(d * 4 + p) * 8];
      }
      do_tile(ks, qB, quad, c16, qB0, qB1, kf, vb, lB, oB);
      if (ks < nkA)
        do_tile(ks, qA, quad, c16, qA0, qA1, kf, vb, lA, oA);
    }
    __syncthreads();
    if (more) {
      *(s16x8*)&Kl[ci * 8] = kreg;
      *(s16x8*)&Vl[ci * 8] = vreg;
      __syncthreads();
    }
  }

  lB += __shfl_xor(lB, 16, 64); lB += __shfl_xor(lB, 32, 64);
  lA += __shfl_xor(lA, 16, 64); lA += __shfl_xor(lA, 32, 64);
  float invB = 1.f / lB, invA = 1.f / lA;
#pragma unroll
  for (int r = 0; r < 4; r++) {
    float ivB = __shfl(invB, quad * 4 + r, 64);
    float ivA = __shfl(invA, quad * 4 + r, 64);
    size_t baseB = (size_t)(b * Tt + qB + quad * 4 + r) * Dd + h * 64;
    size_t baseA = (size_t)(b * Tt + qA + quad * 4 + r) * Dd + h * 64;
#pragma unroll
    for (int nt = 0; nt < 4; nt++) {
      po[baseB + nt * 16 + c16] = f2bf(oB[nt][r] * ivB);
      po[baseA + nt * 16 + c16] = f2bf(oA[nt][r] * ivA);
    }
  }
}

// ---------------- chunked decay scan ----------------

__global__ __launch_bounds__(64) void scanA_kernel(const float* __restrict__ Jw,
                                                   const float* __restrict__ Jr,
                                                   const float* __restrict__ decay_logits,
                                                   float* __restrict__ chunkA) {
  int blk = blockIdx.x;
  int chunk = blk & 15, bh = (blk >> 4) & 31, type = blk >> 9;
  int lane = threadIdx.x;
  const float* V = (type == 0 ? Jw : Jr) + ((size_t)bh * Tt + chunk * 128) * 6;
  __shared__ float v[768];
  for (int i = lane; i < 768; i += 64) v[i] = V[i];
  __syncthreads();
  float d = sigm(decay_logits[bh & 15]);
  int ll = lane < 36 ? lane : 35;
  int i6 = ll / 6, j6 = ll % 6;
  float A = 0.f;
  for (int s = 0; s < 128; s++) A = d * A + v[s * 6 + i6] * v[s * 6 + j6];
  if (lane < 36) chunkA[((size_t)(type * 32 + bh) * 16 + chunk) * 36 + lane] = A;
}

// scanB with inline cross-chunk prefix:
// B_chunk = sum_{c<chunk} dS^(chunk-1-c) * d * chunkA[c]
// score(t) = d^tl * (u^T B u) + sum_{s<tl} d^(tl-s) (u.w_s)^2

__global__ __launch_bounds__(128) void scanB_kernel(const float* __restrict__ Jw,
                                                    const float* __restrict__ Jr,
                                                    const float* __restrict__ rd,
                                                    const float* __restrict__ chunkA,
                                                    const float* __restrict__ decay_logits,
                                                    float* __restrict__ score_w,
                                                    float* __restrict__ score_r) {
  int blk = blockIdx.x;
  int chunk = blk & 15, bh = (blk >> 4) & 31, type = blk >> 9;
  int tl = threadIdx.x;
  size_t tb = ((size_t)bh * Tt + chunk * 128) * 6;
  const float* U = (type == 0 ? rd : Jw) + tb;
  const float* W = (type == 0 ? Jw : Jr) + tb;
  __shared__ float wv[768];
  __shared__ float Bm[36];
  for (int i = tl; i < 768; i += 128) wv[i] = W[i];
  float d = sigm(decay_logits[bh & 15]);
  if (tl < 36) {
    float dS = powf(d, 128.f);
    float Bv = 0.f;
    size_t base = (size_t)(type * 32 + bh) * 16;
    for (int c = 0; c < chunk; c++)
      Bv = dS * Bv + d * chunkA[(base + c) * 36 + tl];
    Bm[tl] = Bv;
  }
  __syncthreads();
  float u[6];
#pragma unroll
  for (int i = 0; i < 6; i++) u[i] = U[tl * 6 + i];
  float q = 0.f;
#pragma unroll
  for (int i = 0; i < 6; i++) {
    float bi = 0.f;
#pragma unroll
    for (int j = 0; j < 6; j++) bi += Bm[i * 6 + j] * u[j];
    q += u[i] * bi;
  }
  float acc = 0.f;
  for (int s = 0; s < tl; s++) {
    const float* ws = &wv[s * 6];
    float dot = u[0]*ws[0] + u[1]*ws[1] + u[2]*ws[2] + u[3]*ws[3] + u[4]*ws[4] + u[5]*ws[5];
    acc = d * (acc + dot * dot);
  }
  float score = acc + powf(d, (float)tl) * q;
  float* outp = (type == 0 ? score_w : score_r);
  outp[(size_t)bh * Tt + chunk * 128 + tl] = score;
}

// ---------------- gate + combine (writes A-fragment-major fused) --------------

__global__ __launch_bounds__(256) void combine_kernel(const unsigned short* __restrict__ po,
                                                      const unsigned short* __restrict__ Cq,
                                                      const float* __restrict__ score_w,
                                                      const float* __restrict__ score_r,
                                                      const float* __restrict__ mem_scale,
                                                      const float* __restrict__ rw_mix,
                                                      unsigned short* __restrict__ fused) {
  __shared__ float tmp[16];
  int rowi = blockIdx.x;
  int b = rowi >> 11, t = rowi & 2047;
  float alpha = sigm(rw_mix[0]);
  if (threadIdx.x < 16) {
    int h = threadIdx.x;
    size_t sh = (size_t)(b * 16 + h) * Tt + t;
    float ms = (1.f - alpha) * score_w[sh] + alpha * score_r[sh];
    float gate = sigm(bf2f(Cq[(size_t)rowi * LDC + 3328 + h]));
    tmp[h] = sigm(ms * mem_scale[h]) * gate;
  }
  __syncthreads();
  float g = 0.f;
#pragma unroll
  for (int h = 0; h < 16; h++) g += tmp[h];
  g *= (1.f / 16.f);
  if (threadIdx.x < 128) {
    int c = threadIdx.x;          // 8-elem chunk, d = c*8..+8
    int d0 = c * 8;
    s16x8 ov = *(const s16x8*)&po[((size_t)b * Tt + t) * Dd + d0];
    s16x8 mv = *(const s16x8*)&Cq[(size_t)rowi * LDC + 3392 + d0];
    s16x8 out;
#pragma unroll
    for (int e = 0; e < 8; e++)
      out[e] = (short)f2bf(bf2f((unsigned short)ov[e]) + g * bf2f((unsigned short)mv[e]));
    int mt = rowi >> 4, kt = c >> 2, quad = c & 3;
    int lane = (rowi & 15) + quad * 16;
    *(s16x8*)&fused[(((size_t)mt * 32 + kt) * 64 + lane) * 8] = out;
  }
}

// ---------------- launch ----------------

extern "C" void kernel_launch(void* const* d_in, const int* in_sizes, int n_in,
                              void* d_out, int out_size, void* d_ws, size_t ws_size,
                              hipStream_t stream) {
  (void)in_sizes; (void)n_in; (void)out_size; (void)ws_size;
  const float* x         = (const float*)d_in[0];
  const float* qkv_w     = (const float*)d_in[1];
  const float* qkv_b     = (const float*)d_in[2];
  const float* w1w       = (const float*)d_in[3];
  const float* w2w       = (const float*)d_in[4];
  const float* w1r       = (const float*)d_in[5];
  const float* w2r       = (const float*)d_in[6];
  const float* memv_w    = (const float*)d_in[7];
  const float* memv_b    = (const float*)d_in[8];
  const float* memg_w    = (const float*)d_in[9];
  const float* memg_b    = (const float*)d_in[10];
  const float* mem_scale = (const float*)d_in[11];
  const float* rw_mix    = (const float*)d_in[12];
  const float* out_w     = (const float*)d_in[13];
  const float* out_b     = (const float*)d_in[14];
  const float* decay_l   = (const float*)d_in[15];

  char* w = (char*)d_ws;
  unsigned short* xb    = (unsigned short*)(w + 0);          //  8388608  A-frags
  unsigned short* Kt    = (unsigned short*)(w + 0);          //  overlay (xb dead after gemm)
  unsigned short* WT    = (unsigned short*)(w + 8388608);    //  9175040  B-frags (280 nt)
  unsigned short* Vt    = (unsigned short*)(w + 8388608);    //  overlay (WT dead after gemm)
  unsigned short* outT  = (unsigned short*)(w + 17563648);   //  2097152  B-frags (64 nt)
  float*          biasC = (float*)(w + 19660800);            //    17920
  unsigned short* Cbuf  = (unsigned short*)(w + 19678720);   // 36700160
  unsigned short* po    = (unsigned short*)(w + 56378880);   //  8388608
  float*          Jw    = (float*)(w + 73680384);            //  1572864
  float*          Jr    = (float*)(w + 75253248);            //  1572864
  float*          rd    = (float*)(w + 76826112);            //  1572864
  float*          chA   = (float*)(w + 78398976);            //   147456
  float*          sw    = (float*)(w + 78693888);            //   262144
  float*          sr    = (float*)(w + 78956032);            //   262144
  unsigned short* fused = (unsigned short*)(w + 79218176);   //  8388608  A-frags

  prep_kernel<<<7570, 256, 0, stream>>>(x, qkv_w, w1w, w2w, w1r, w2r, memg_w, memv_w,
                                        out_w, qkv_b, memg_b, memv_b,
                                        xb, WT, outT, biasC);

  gemm_frag_kernel<0><<<1152, 256, 0, stream>>>(xb, WT, Cbuf, biasC);

  post1_kernel<<<2304, 256, 0, stream>>>(Cbuf, Kt, Vt, Jw, Jr, rd);
  attn_kernel<<<dim3(16, 32), 256, 0, stream>>>(Cbuf, Kt, Vt, po);
  scanA_kernel<<<1024, 64, 0, stream>>>(Jw, Jr, decay_l, chA);
  scanB_kernel<<<1024, 128, 0, stream>>>(Jw, Jr, rd, chA, decay_l, sw, sr);
  combine_kernel<<<4096, 256, 0, stream>>>(po, Cbuf, sw, sr, mem_scale, rw_mix, fused);

  gemm_frag_kernel<1><<<256, 256, 0, stream>>>(fused, outT, d_out, out_b);
}